// Round 16
// baseline (539.344 us; speedup 1.0000x reference)
//
#include <hip/hip_runtime.h>

// VQ-VAE fused forward. Output f32 layout:
//   s_hat : [0,          31457280)   B x 120
//   z_e   : [31457280,   48234496)   B x 64
//   emb   : [48234496,   65011712)   B x 64
//   argmin: [65011712,   65273856)   B
//
// MFMA fast path (hi/lo bf16 split, 3 products hh+hl+lh); rows with top-2
// distance gap < THR re-run through the np-exact fp32 path.
// R16: G1/G2 8-wave x (16row x 64col) tiles (acc[4], halved A-LDS traffic);
// G3+G4 fused via precomputed W4 = ew3@cbT and cn2 (no z re-split, no
// zh/zl staging, 2 fewer barriers). (512,4), spill-free target.

#define B_TOTAL 262144
#define THR 0.02f

typedef float  f32x4 __attribute__((ext_vector_type(4)));
typedef short  s16x8 __attribute__((ext_vector_type(8)));

#define ZB ((size_t)B_TOTAL * 120)
#define EB ((size_t)B_TOTAL * 184)
#define AB ((size_t)B_TOTAL * 248)

// ---- ws layout (bytes) ----
#define WS_STAB   0         // f32[64*120]   30720
#define WS_CBT    30720     // f32[64*64]    16384
#define WS_CNORM  47104     // f32[64]         256
#define WS_COUNT  47360     // int             64
#define WS_LIST   47424     // int[262144] 1048576
#define WS_PKW1   1096064   // 131072
#define WS_PKW2   1227136   // 262144
#define WS_PKE3   1489280   // 65536
#define WS_PKW4   1554816   // 65536  (W4 = ew3 @ cbT, packed hi/lo)
#define WS_CN2    1620352   // f32[64] 256

static __device__ __forceinline__ unsigned short f2bf(float x) {
    unsigned int u = __float_as_uint(x);
    return (unsigned short)((u + 0x7fffu + ((u >> 16) & 1u)) >> 16);   // RTNE
}
// RTNE split (pack kernel only — once on weights)
static __device__ __forceinline__ void splitbf(float a, unsigned short& h, unsigned short& s) {
    unsigned hb = __float_as_uint(a) & 0xffff0000u;
    h = (unsigned short)(hb >> 16);
    s = f2bf(a - __uint_as_float(hb));
}
// truncated-lo split (fast kernel): 4 VALU ops, err <= 2^-17 * |a|
static __device__ __forceinline__ void splitbf_t(float a, unsigned short& h, unsigned short& s) {
    unsigned u = __float_as_uint(a);
    h = (unsigned short)(u >> 16);
    float d = a - __uint_as_float(u & 0xffff0000u);
    s = (unsigned short)(__float_as_uint(d) >> 16);
}
static __device__ __forceinline__ float sqnc(float v) {
    float s = v * v;
    asm volatile("" : "+v"(s));
    return s;
}
static __device__ __forceinline__ float np_sumsq64(const float* a) {
    float r8[8];
#pragma unroll
    for (int j = 0; j < 8; ++j) r8[j] = sqnc(a[j]);
#pragma unroll
    for (int i = 8; i < 64; i += 8)
#pragma unroll
        for (int j = 0; j < 8; ++j) r8[j] += sqnc(a[i + j]);
    return ((r8[0] + r8[1]) + (r8[2] + r8[3])) + ((r8[4] + r8[5]) + (r8[6] + r8[7]));
}

// swizzled short-index within a [32][256]-short plane (16B-granule XOR)
static __device__ __forceinline__ int swz(int row, int col) {
    return row * 256 + ((((col >> 3) ^ (row & 7))) << 3) + (col & 7);
}

// ---------------------------------------------------------------------------
// P1: decode tables (np-exact). grid 64 x 256.  [proven]
// ---------------------------------------------------------------------------
__global__ __launch_bounds__(256)
void vq_prep(const float* __restrict__ cb,
             const float* __restrict__ dw3, const float* __restrict__ db3,
             const float* __restrict__ dw4, const float* __restrict__ db4,
             const float* __restrict__ dw5, const float* __restrict__ db5,
             float* __restrict__ s_tab, float* __restrict__ cbT, float* __restrict__ cnorm)
{
    __shared__ float c_row[64];
    __shared__ float u1[256];
    __shared__ float u2[256];
    const int k = blockIdx.x;
    const int t = threadIdx.x;

    if (t < 64) c_row[t] = cb[k * 64 + t];
    __syncthreads();
    {
        float s = 0.f;
        for (int f = 0; f < 64; ++f) s = fmaf(c_row[f], dw3[f * 256 + t], s);
        u1[t] = fmaxf(s + db3[t], 0.f);
    }
    if (t < 64) cbT[t * 64 + k] = c_row[t];
    if (t == 0) cnorm[k] = np_sumsq64(&cb[k * 64]);
    __syncthreads();
    {
        float s = 0.f;
        for (int f = 0; f < 256; ++f) s = fmaf(u1[f], dw4[f * 256 + t], s);
        u2[t] = fmaxf(s + db4[t], 0.f);
    }
    __syncthreads();
    if (t < 120) {
        float o = 0.f;
        for (int f = 0; f < 256; ++f) o = fmaf(u2[f], dw5[f * 120 + t], o);
        s_tab[k * 120 + t] = o + db5[t];
    }
}

// ---------------------------------------------------------------------------
// P2: pack weights into MFMA B-frag layout (hi/lo bf16) + W4 + cn2.
// grid 256 x 512. Blocks: [0,64) w1, [64,192) w2, [192,224) ew3,
// [224,256) W4 = ew3 @ cbT (computed from cb directly).
// ---------------------------------------------------------------------------
__global__ __launch_bounds__(512)
void vq_pack(const float* __restrict__ w1, const float* __restrict__ w2,
             const float* __restrict__ ew3, const float* __restrict__ cb,
             const float* __restrict__ eb3,
             unsigned short* __restrict__ pw1, unsigned short* __restrict__ pw2,
             unsigned short* __restrict__ pe3, unsigned short* __restrict__ pw4,
             float* __restrict__ cn2, int* __restrict__ flag_count)
{
    const int t = threadIdx.x;
    int f = blockIdx.x;
    if (f == 0 && t == 0) *flag_count = 0;

    const int lane = t >> 3, j = t & 7;
    float a;
    unsigned short* dst;
    int nt, ks, KSN;

    if (f < 224) {
        const float* src; int srcK, ld;
        if (f < 64)       { src = w1;  dst = pw1; KSN = 4; nt = f >> 2;  ks = f & 3; srcK = 120; ld = 256; }
        else if (f < 192) { f -= 64;  src = w2;  dst = pw2; KSN = 8; nt = f >> 3; ks = f & 7; srcK = 256; ld = 256; }
        else              { f -= 192; src = ew3; dst = pe3; KSN = 8; nt = f >> 3; ks = f & 7; srcK = 256; ld = 64; }
        const int k = ks * 32 + (lane >> 4) * 8 + j;
        const int n = nt * 16 + (lane & 15);
        a = (k < srcK) ? src[k * ld + n] : 0.f;
    } else {
        // W4[k][n] = sum_d ew3[k][d] * cb[n][d]   (k<256, n<64)
        int g = f - 224;
        dst = pw4; KSN = 8; nt = g >> 3; ks = g & 7;
        const int k = ks * 32 + (lane >> 4) * 8 + j;
        const int n = nt * 16 + (lane & 15);
        float s = 0.f;
        const float* er = ew3 + k * 64;
        const float* cr = cb + n * 64;
        for (int d = 0; d < 64; ++d) s = fmaf(er[d], cr[d], s);
        a = s;
        // cn2 (fast-path constant): one block computes it
        if (g == 0 && t < 64) {
            float ss = 0.f, e2 = 0.f;
            const float* c = cb + t * 64;
            for (int d = 0; d < 64; ++d) { ss = fmaf(c[d], c[d], ss); e2 = fmaf(eb3[d], c[d], e2); }
            cn2[t] = ss - 2.f * e2;
        }
    }

    unsigned short h, l;
    splitbf(a, h, l);
    const int base = (nt * KSN + ks) * 2 * 512;
    dst[base + t] = h;
    dst[base + 512 + t] = l;
}

// ---------------------------------------------------------------------------
// Fast kernel: 32 rows/block, 512 threads (8 waves), 32KB LDS, (512,4).
// G1/G2: wave w -> rows (w&1)*16 (1 rt), cols (w>>1)*64 (4 ct) -> acc[4].
// G3+G4 fused: wave w -> rows (w&1)*16, cols (w>>1)*16 for BOTH z and dist;
// dist = cn2 - 2*(h2 @ W4) read directly from the h2 planes.
// ---------------------------------------------------------------------------
__global__ __launch_bounds__(512, 4)
void vq_fast(const float* __restrict__ x,
             const float* __restrict__ b1, const float* __restrict__ b2,
             const float* __restrict__ eb3, const float* __restrict__ cb,
             const float* __restrict__ s_tab, const float* __restrict__ cn2,
             const unsigned short* __restrict__ pw1, const unsigned short* __restrict__ pw2,
             const unsigned short* __restrict__ pe3, const unsigned short* __restrict__ pw4,
             int* __restrict__ flag_count, int* __restrict__ flag_list,
             float* __restrict__ out)
{
    __shared__ __align__(16) unsigned char smem[32768];
    unsigned short* ph = (unsigned short*)smem;             // hi plane [32][256] swz
    unsigned short* pl = (unsigned short*)(smem + 16384);   // lo plane [32][256] swz
    float*          dm = (float*)smem;                      // dmat [32][68] (aliased, post-G3G4)
    int*          idxs = (int*)(smem + 8704);               // [32]          (aliased)

    const int t = threadIdx.x;
    const int w = t >> 6, l = t & 63;
    const int lr = l & 15;
    const int grow0 = blockIdx.x * 32;

    // ---- stage x -> hi/lo planes (swizzled; cols 0..119, pad 120..127 = 0)
    {
        const float* xb = x + (size_t)grow0 * 120;
        unsigned* ph32 = (unsigned*)ph;
        unsigned* pl32 = (unsigned*)pl;
#pragma unroll
        for (int i = 0; i < 4; ++i) {
            int p = t + 512 * i;             // pair index 0..2047
            if (p < 1920) {
                int row = p / 60, c2 = p - row * 60;
                float2 v = *(const float2*)&xb[row * 120 + c2 * 2];
                unsigned u0 = __float_as_uint(v.x);
                unsigned u1 = __float_as_uint(v.y);
                unsigned h0u = u0 & 0xffff0000u;
                unsigned h1u = u1 & 0xffff0000u;
                float d0 = v.x - __uint_as_float(h0u);
                float d1 = v.y - __uint_as_float(h1u);
                int o32 = row * 128 + ((((c2 >> 2) ^ (row & 7))) << 2) + (c2 & 3);
                ph32[o32] = (u0 >> 16) | h1u;
                pl32[o32] = (__float_as_uint(d0) >> 16) | (__float_as_uint(d1) & 0xffff0000u);
            }
        }
        if (t < 128) {
            int row = t >> 2, c2 = 60 + (t & 3);
            int o32 = row * 128 + ((((c2 >> 2) ^ (row & 7))) << 2) + (c2 & 3);
            ph32[o32] = 0u;
            pl32[o32] = 0u;
        }
    }
    __syncthreads();

    const int wrow = w & 1, wcol = w >> 1;
    const int rA = wrow * 16 + lr;          // A-frag row for this wave

    // ================= GEMM1: h1 = relu(x @ w1 + b1), K=128(pad) ============
    {
        f32x4 acc[4];
#pragma unroll
        for (int b = 0; b < 4; ++b) acc[b] = (f32x4)0.f;

#pragma unroll
        for (int ks = 0; ks < 4; ++ks) {
            const int kb = ks * 32 + (l >> 4) * 8;
            const int ro = swz(rA, kb);
            s16x8 ah = *(const s16x8*)&ph[ro];
            s16x8 al = *(const s16x8*)&pl[ro];
#pragma unroll
            for (int cp = 0; cp < 2; ++cp) {
                s16x8 bh[2], bl[2];
#pragma unroll
                for (int j = 0; j < 2; ++j) {
                    const unsigned short* pb = pw1 + ((wcol * 4 + cp * 2 + j) * 4 + ks) * 1024 + l * 8;
                    bh[j] = *(const s16x8*)pb;
                    bl[j] = *(const s16x8*)(pb + 512);
                }
                __builtin_amdgcn_s_setprio(1);
#pragma unroll
                for (int j = 0; j < 2; ++j) {
                    const int ct = cp * 2 + j;
                    acc[ct] = __builtin_amdgcn_mfma_f32_16x16x32_bf16(ah, bh[j], acc[ct], 0, 0, 0);
                    acc[ct] = __builtin_amdgcn_mfma_f32_16x16x32_bf16(ah, bl[j], acc[ct], 0, 0, 0);
                    acc[ct] = __builtin_amdgcn_mfma_f32_16x16x32_bf16(al, bh[j], acc[ct], 0, 0, 0);
                }
                __builtin_amdgcn_s_setprio(0);
            }
        }
        __syncthreads();
#pragma unroll
        for (int ct = 0; ct < 4; ++ct) {
            const int col = wcol * 64 + ct * 16 + lr;
            const float bb = b1[col];
#pragma unroll
            for (int r = 0; r < 4; ++r) {
                float v = fmaxf(acc[ct][r] + bb, 0.f);
                unsigned short h, s;
                splitbf_t(v, h, s);
                const int row = wrow * 16 + (l >> 4) * 4 + r;
                const int o = swz(row, col);
                ph[o] = h;
                pl[o] = s;
            }
        }
    }
    __syncthreads();

    // ================= GEMM2: h2 = relu(h1 @ w2 + b2), K=256 ================
    {
        f32x4 acc[4];
#pragma unroll
        for (int b = 0; b < 4; ++b) acc[b] = (f32x4)0.f;

#pragma unroll
        for (int ks = 0; ks < 8; ++ks) {
            const int kb = ks * 32 + (l >> 4) * 8;
            const int ro = swz(rA, kb);
            s16x8 ah = *(const s16x8*)&ph[ro];
            s16x8 al = *(const s16x8*)&pl[ro];
#pragma unroll
            for (int cp = 0; cp < 2; ++cp) {
                s16x8 bh[2], bl[2];
#pragma unroll
                for (int j = 0; j < 2; ++j) {
                    const unsigned short* pb = pw2 + ((wcol * 4 + cp * 2 + j) * 8 + ks) * 1024 + l * 8;
                    bh[j] = *(const s16x8*)pb;
                    bl[j] = *(const s16x8*)(pb + 512);
                }
                __builtin_amdgcn_s_setprio(1);
#pragma unroll
                for (int j = 0; j < 2; ++j) {
                    const int ct = cp * 2 + j;
                    acc[ct] = __builtin_amdgcn_mfma_f32_16x16x32_bf16(ah, bh[j], acc[ct], 0, 0, 0);
                    acc[ct] = __builtin_amdgcn_mfma_f32_16x16x32_bf16(ah, bl[j], acc[ct], 0, 0, 0);
                    acc[ct] = __builtin_amdgcn_mfma_f32_16x16x32_bf16(al, bh[j], acc[ct], 0, 0, 0);
                }
                __builtin_amdgcn_s_setprio(0);
            }
        }
        __syncthreads();
#pragma unroll
        for (int ct = 0; ct < 4; ++ct) {
            const int col = wcol * 64 + ct * 16 + lr;
            const float bb = b2[col];
#pragma unroll
            for (int r = 0; r < 4; ++r) {
                float v = fmaxf(acc[ct][r] + bb, 0.f);
                unsigned short h, s;
                splitbf_t(v, h, s);
                const int row = wrow * 16 + (l >> 4) * 4 + r;
                const int o = swz(row, col);
                ph[o] = h;
                pl[o] = s;
            }
        }
    }
    __syncthreads();

    // ===== G3+G4 fused: z = h2@ew3 + eb3 ; dist = cn2 - 2*(h2@W4), K=256 ====
    {
        f32x4 a3 = (f32x4)0.f;
        f32x4 a4 = (f32x4)0.f;

#pragma unroll
        for (int ks = 0; ks < 8; ++ks) {
            const int kb = ks * 32 + (l >> 4) * 8;
            const int ro = swz(rA, kb);
            s16x8 ah = *(const s16x8*)&ph[ro];
            s16x8 al = *(const s16x8*)&pl[ro];
            const unsigned short* pb3 = pe3 + (wcol * 8 + ks) * 1024 + l * 8;
            const unsigned short* pb4 = pw4 + (wcol * 8 + ks) * 1024 + l * 8;
            s16x8 bh3 = *(const s16x8*)pb3;
            s16x8 bl3 = *(const s16x8*)(pb3 + 512);
            s16x8 bh4 = *(const s16x8*)pb4;
            s16x8 bl4 = *(const s16x8*)(pb4 + 512);
            __builtin_amdgcn_s_setprio(1);
            a3 = __builtin_amdgcn_mfma_f32_16x16x32_bf16(ah, bh3, a3, 0, 0, 0);
            a3 = __builtin_amdgcn_mfma_f32_16x16x32_bf16(ah, bl3, a3, 0, 0, 0);
            a3 = __builtin_amdgcn_mfma_f32_16x16x32_bf16(al, bh3, a3, 0, 0, 0);
            a4 = __builtin_amdgcn_mfma_f32_16x16x32_bf16(ah, bh4, a4, 0, 0, 0);
            a4 = __builtin_amdgcn_mfma_f32_16x16x32_bf16(ah, bl4, a4, 0, 0, 0);
            a4 = __builtin_amdgcn_mfma_f32_16x16x32_bf16(al, bh4, a4, 0, 0, 0);
            __builtin_amdgcn_s_setprio(0);
        }
        __syncthreads();   // all plane reads done -> dm alias region usable

        const int col = wcol * 16 + lr;
        const float eb = eb3[col];
        const float cn = cn2[col];
#pragma unroll
        for (int r = 0; r < 4; ++r) {
            const int row = wrow * 16 + (l >> 4) * 4 + r;
            out[ZB + (size_t)(grow0 + row) * 64 + col] = a3[r] + eb;
            dm[row * 68 + col] = cn - 2.f * a4[r];
        }
    }
    __syncthreads();

    // ===== per-row argmin + gap flag =======================================
    if (t < 32) {
        const float* dr = dm + t * 68;
        float best = dr[0], sec = 3.4e38f;
        int bi = 0;
        for (int j = 1; j < 64; ++j) {
            float v = dr[j];
            if (v < best) { sec = best; best = v; bi = j; }
            else if (v < sec) sec = v;
        }
        idxs[t] = bi;
        out[AB + grow0 + t] = (float)bi;
        if (sec - best < THR) {
            int p = atomicAdd(flag_count, 1);
            if (p < B_TOTAL) flag_list[p] = grow0 + t;
        }
    }
    __syncthreads();

    // ===== gathers: emb + s_hat ============================================
#pragma unroll
    for (int i = 0; i < 4; ++i) {
        int p = t + 512 * i;              // 0..2047
        int row = p >> 6, c = p & 63;
        out[EB + (size_t)blockIdx.x * 2048 + p] = cb[idxs[row] * 64 + c];
    }
#pragma unroll
    for (int i = 0; i < 8; ++i) {
        int p = t + 512 * i;              // 0..4095
        if (p < 3840) {
            int row = p / 120, c = p - row * 120;
            out[(size_t)blockIdx.x * 3840 + p] = s_tab[idxs[row] * 120 + c];
        }
    }
}

// ---------------------------------------------------------------------------
// Exact fallback: np-exact math over flagged rows, 16 rows/block, grid 1024.
// [proven round 9 verbatim]
// ---------------------------------------------------------------------------
__global__ __launch_bounds__(256)
void vq_exact(const float* __restrict__ x,
              const float* __restrict__ w1, const float* __restrict__ b1,
              const float* __restrict__ w2, const float* __restrict__ b2,
              const float* __restrict__ ew3, const float* __restrict__ eb3,
              const float* __restrict__ cb,
              const float* __restrict__ s_tab,
              const float* __restrict__ cbT, const float* __restrict__ cnorm,
              const int* __restrict__ flag_count, const int* __restrict__ flag_list,
              float* __restrict__ out)
{
    __shared__ float act[256 * 18];
    __shared__ float zrm[16 * 68];
    __shared__ float dmr[16 * 68];
    __shared__ float A_lds[16];
    __shared__ int   idxs[16];
    __shared__ int   rl[16];

    const int t = threadIdx.x;
    int count = *flag_count;
    if (count > B_TOTAL) count = B_TOTAL;

    const int tx = t & 31;
    const int ty = t >> 5;
    const int r0 = ty * 2;
    const int c0 = tx * 8;
    const int c0d = tx * 2;

    for (int base = blockIdx.x * 16; base < count; base += 1024 * 16) {
        if (t < 16) {
            int li = base + t;
            rl[t] = flag_list[li < count ? li : count - 1];
        }
        __syncthreads();

        for (int i = 0; i < 8; ++i) {
            int p = t + 256 * i;
            if (p < 1920) {
                int r = p / 120;
                int c = p - r * 120;
                act[c * 18 + r] = x[(size_t)rl[r] * 120 + c];
            }
        }
        __syncthreads();

        // GEMM1: K=120
        {
            float acc[2][8];
#pragma unroll
            for (int i = 0; i < 2; ++i)
#pragma unroll
                for (int c = 0; c < 8; ++c) acc[i][c] = 0.f;
#pragma unroll 2
            for (int k = 0; k < 120; ++k) {
                const float2 av = *(const float2*)&act[k * 18 + r0];
                const float4 wv0 = *(const float4*)&w1[k * 256 + c0];
                const float4 wv1 = *(const float4*)&w1[k * 256 + c0 + 4];
                const float a[2] = {av.x, av.y};
                const float wv[8] = {wv0.x, wv0.y, wv0.z, wv0.w, wv1.x, wv1.y, wv1.z, wv1.w};
#pragma unroll
                for (int i = 0; i < 2; ++i)
#pragma unroll
                    for (int c = 0; c < 8; ++c) acc[i][c] = fmaf(a[i], wv[c], acc[i][c]);
            }
            __syncthreads();
            const float4 bv0 = *(const float4*)&b1[c0];
            const float4 bv1 = *(const float4*)&b1[c0 + 4];
            const float bb[8] = {bv0.x, bv0.y, bv0.z, bv0.w, bv1.x, bv1.y, bv1.z, bv1.w};
#pragma unroll
            for (int c = 0; c < 8; ++c)
#pragma unroll
                for (int i = 0; i < 2; ++i)
                    act[(c0 + c) * 18 + r0 + i] = fmaxf(acc[i][c] + bb[c], 0.f);
        }
        __syncthreads();

        // GEMM2: K=256
        {
            float acc[2][8];
#pragma unroll
            for (int i = 0; i < 2; ++i)
#pragma unroll
                for (int c = 0; c < 8; ++c) acc[i][c] = 0.f;
#pragma unroll 2
            for (int k = 0; k < 256; ++k) {
                const float2 av = *(const float2*)&act[k * 18 + r0];
                const float4 wv0 = *(const float4*)&w2[k * 256 + c0];
                const float4 wv1 = *(const float4*)&w2[k * 256 + c0 + 4];
                const float a[2] = {av.x, av.y};
                const float wv[8] = {wv0.x, wv0.y, wv0.z, wv0.w, wv1.x, wv1.y, wv1.z, wv1.w};
#pragma unroll
                for (int i = 0; i < 2; ++i)
#pragma unroll
                    for (int c = 0; c < 8; ++c) acc[i][c] = fmaf(a[i], wv[c], acc[i][c]);
            }
            __syncthreads();
            const float4 bv0 = *(const float4*)&b2[c0];
            const float4 bv1 = *(const float4*)&b2[c0 + 4];
            const float bb[8] = {bv0.x, bv0.y, bv0.z, bv0.w, bv1.x, bv1.y, bv1.z, bv1.w};
#pragma unroll
            for (int c = 0; c < 8; ++c)
#pragma unroll
                for (int i = 0; i < 2; ++i)
                    act[(c0 + c) * 18 + r0 + i] = fmaxf(acc[i][c] + bb[c], 0.f);
        }
        __syncthreads();

        // GEMM3: K=256, 64 cols
        {
            float acc2[2][2];
#pragma unroll
            for (int i = 0; i < 2; ++i) { acc2[i][0] = 0.f; acc2[i][1] = 0.f; }
#pragma unroll 2
            for (int k = 0; k < 256; ++k) {
                const float2 av = *(const float2*)&act[k * 18 + r0];
                const float2 wv = *(const float2*)&ew3[k * 64 + c0d];
#pragma unroll
                for (int i = 0; i < 2; ++i) {
                    float a = (i == 0) ? av.x : av.y;
                    acc2[i][0] = fmaf(a, wv.x, acc2[i][0]);
                    acc2[i][1] = fmaf(a, wv.y, acc2[i][1]);
                }
            }
            __syncthreads();
            const float2 bv = *(const float2*)&eb3[c0d];
#pragma unroll
            for (int i = 0; i < 2; ++i) {
                float z0 = acc2[i][0] + bv.x;
                float z1 = acc2[i][1] + bv.y;
                act[(c0d + 0) * 18 + r0 + i] = z0;
                act[(c0d + 1) * 18 + r0 + i] = z1;
                zrm[(r0 + i) * 68 + c0d]     = z0;
                zrm[(r0 + i) * 68 + c0d + 1] = z1;
            }
        }
        __syncthreads();

        if (t < 16) A_lds[t] = np_sumsq64(&zrm[t * 68]);
        __syncthreads();

        {
            float acc3[2][2];
#pragma unroll
            for (int i = 0; i < 2; ++i) { acc3[i][0] = 0.f; acc3[i][1] = 0.f; }
#pragma unroll 2
            for (int k = 0; k < 64; ++k) {
                const float2 av = *(const float2*)&act[k * 18 + r0];
                const float2 wv = *(const float2*)&cbT[k * 64 + c0d];
#pragma unroll
                for (int i = 0; i < 2; ++i) {
                    float a = (i == 0) ? av.x : av.y;
                    acc3[i][0] = fmaf(a, wv.x, acc3[i][0]);
                    acc3[i][1] = fmaf(a, wv.y, acc3[i][1]);
                }
            }
            const float cn0 = cnorm[c0d], cn1 = cnorm[c0d + 1];
#pragma unroll
            for (int i = 0; i < 2; ++i) {
                float g0 = 2.0f * acc3[i][0];  asm volatile("" : "+v"(g0));
                float g1 = 2.0f * acc3[i][1];  asm volatile("" : "+v"(g1));
                const float Ar = A_lds[r0 + i];
                dmr[(r0 + i) * 68 + c0d]     = (Ar - g0) + cn0;
                dmr[(r0 + i) * 68 + c0d + 1] = (Ar - g1) + cn1;
            }
        }
        __syncthreads();

        if (t < 16) {
            const float* dr = &dmr[t * 68];
            float best = dr[0];
            int bi = 0;
            for (int c = 1; c < 64; ++c) {
                float v = dr[c];
                if (v < best) { best = v; bi = c; }
            }
            idxs[t] = bi;
            out[AB + rl[t]] = (float)bi;
        }
        __syncthreads();

        {
            const int r = t >> 4, q = t & 15;
            *(float4*)(out + ZB + (size_t)rl[r] * 64 + q * 4) = *(const float4*)&zrm[r * 68 + q * 4];
        }
        {
            const int r = t >> 4, q = t & 15;
            *(float4*)(out + EB + (size_t)rl[r] * 64 + q * 4) = *(const float4*)(cb + idxs[r] * 64 + q * 4);
        }
        for (int i = 0; i < 8; ++i) {
            int p = t + 256 * i;
            if (p < 1920) {
                int r = p / 120;
                int c = p - r * 120;
                out[(size_t)rl[r] * 120 + c] = s_tab[idxs[r] * 120 + c];
            }
        }
        __syncthreads();
    }
}

// ---------------------------------------------------------------------------
extern "C" void kernel_launch(void* const* d_in, const int* in_sizes, int n_in,
                              void* d_out, int out_size, void* d_ws, size_t ws_size,
                              hipStream_t stream)
{
    const float* x   = (const float*)d_in[0];
    const float* w1  = (const float*)d_in[1];
    const float* b1  = (const float*)d_in[2];
    const float* w2  = (const float*)d_in[3];
    const float* b2  = (const float*)d_in[4];
    const float* ew3 = (const float*)d_in[5];
    const float* eb3 = (const float*)d_in[6];
    const float* cb  = (const float*)d_in[7];
    const float* dw3 = (const float*)d_in[8];
    const float* db3 = (const float*)d_in[9];
    const float* dw4 = (const float*)d_in[10];
    const float* db4 = (const float*)d_in[11];
    const float* dw5 = (const float*)d_in[12];
    const float* db5 = (const float*)d_in[13];

    float* out = (float*)d_out;
    char* ws = (char*)d_ws;
    float* s_tab = (float*)(ws + WS_STAB);
    float* cbT   = (float*)(ws + WS_CBT);
    float* cnorm = (float*)(ws + WS_CNORM);
    int*   fcnt  = (int*)(ws + WS_COUNT);
    int*   flist = (int*)(ws + WS_LIST);
    unsigned short* pw1 = (unsigned short*)(ws + WS_PKW1);
    unsigned short* pw2 = (unsigned short*)(ws + WS_PKW2);
    unsigned short* pe3 = (unsigned short*)(ws + WS_PKE3);
    unsigned short* pw4 = (unsigned short*)(ws + WS_PKW4);
    float* cn2 = (float*)(ws + WS_CN2);

    vq_prep<<<64, 256, 0, stream>>>(cb, dw3, db3, dw4, db4, dw5, db5,
                                    s_tab, cbT, cnorm);
    vq_pack<<<256, 512, 0, stream>>>(w1, w2, ew3, cb, eb3,
                                     pw1, pw2, pe3, pw4, cn2, fcnt);
    vq_fast<<<B_TOTAL / 32, 512, 0, stream>>>(x, b1, b2, eb3, cb, s_tab, cn2,
                                              pw1, pw2, pe3, pw4, fcnt, flist, out);
    vq_exact<<<1024, 256, 0, stream>>>(x, w1, b1, w2, b2, ew3, eb3, cb,
                                       s_tab, cbT, cnorm, fcnt, flist, out);
}

// Round 17
// 494.149 us; speedup vs baseline: 1.0915x; 1.0915x over previous
//
#include <hip/hip_runtime.h>

// VQ-VAE fused forward. Output f32 layout:
//   s_hat : [0,          31457280)   B x 120
//   z_e   : [31457280,   48234496)   B x 64
//   emb   : [48234496,   65011712)   B x 64
//   argmin: [65011712,   65273856)   B
//
// MFMA fast path (hi/lo bf16 split, 3 products hh+hl+lh); rows with top-2
// distance gap < THR re-run through the np-exact fp32 path.
// R17: r15's proven G1/G2 tiling (8 waves x 32 cols, B-read-once, 64
// issues/ks) + r16's validated W4-fused G3+G4 (no zh/zl staging, -2
// barriers). (512,4), spill-free.

#define B_TOTAL 262144
#define THR 0.02f

typedef float  f32x4 __attribute__((ext_vector_type(4)));
typedef short  s16x8 __attribute__((ext_vector_type(8)));

#define ZB ((size_t)B_TOTAL * 120)
#define EB ((size_t)B_TOTAL * 184)
#define AB ((size_t)B_TOTAL * 248)

// ---- ws layout (bytes) ----
#define WS_STAB   0         // f32[64*120]   30720
#define WS_CBT    30720     // f32[64*64]    16384
#define WS_CNORM  47104     // f32[64]         256
#define WS_COUNT  47360     // int             64
#define WS_LIST   47424     // int[262144] 1048576
#define WS_PKW1   1096064   // 131072
#define WS_PKW2   1227136   // 262144
#define WS_PKE3   1489280   // 65536
#define WS_PKW4   1554816   // 65536  (W4 = ew3 @ cbT, packed hi/lo)
#define WS_CN2    1620352   // f32[64] 256

static __device__ __forceinline__ unsigned short f2bf(float x) {
    unsigned int u = __float_as_uint(x);
    return (unsigned short)((u + 0x7fffu + ((u >> 16) & 1u)) >> 16);   // RTNE
}
// RTNE split (pack kernel only — once on weights)
static __device__ __forceinline__ void splitbf(float a, unsigned short& h, unsigned short& s) {
    unsigned hb = __float_as_uint(a) & 0xffff0000u;
    h = (unsigned short)(hb >> 16);
    s = f2bf(a - __uint_as_float(hb));
}
// truncated-lo split (fast kernel): 4 VALU ops, err <= 2^-17 * |a|
static __device__ __forceinline__ void splitbf_t(float a, unsigned short& h, unsigned short& s) {
    unsigned u = __float_as_uint(a);
    h = (unsigned short)(u >> 16);
    float d = a - __uint_as_float(u & 0xffff0000u);
    s = (unsigned short)(__float_as_uint(d) >> 16);
}
static __device__ __forceinline__ float sqnc(float v) {
    float s = v * v;
    asm volatile("" : "+v"(s));
    return s;
}
static __device__ __forceinline__ float np_sumsq64(const float* a) {
    float r8[8];
#pragma unroll
    for (int j = 0; j < 8; ++j) r8[j] = sqnc(a[j]);
#pragma unroll
    for (int i = 8; i < 64; i += 8)
#pragma unroll
        for (int j = 0; j < 8; ++j) r8[j] += sqnc(a[i + j]);
    return ((r8[0] + r8[1]) + (r8[2] + r8[3])) + ((r8[4] + r8[5]) + (r8[6] + r8[7]));
}

// swizzled short-index within a [32][256]-short plane (16B-granule XOR)
static __device__ __forceinline__ int swz(int row, int col) {
    return row * 256 + ((((col >> 3) ^ (row & 7))) << 3) + (col & 7);
}

// ---------------------------------------------------------------------------
// P1: decode tables (np-exact). grid 64 x 256.  [proven]
// ---------------------------------------------------------------------------
__global__ __launch_bounds__(256)
void vq_prep(const float* __restrict__ cb,
             const float* __restrict__ dw3, const float* __restrict__ db3,
             const float* __restrict__ dw4, const float* __restrict__ db4,
             const float* __restrict__ dw5, const float* __restrict__ db5,
             float* __restrict__ s_tab, float* __restrict__ cbT, float* __restrict__ cnorm)
{
    __shared__ float c_row[64];
    __shared__ float u1[256];
    __shared__ float u2[256];
    const int k = blockIdx.x;
    const int t = threadIdx.x;

    if (t < 64) c_row[t] = cb[k * 64 + t];
    __syncthreads();
    {
        float s = 0.f;
        for (int f = 0; f < 64; ++f) s = fmaf(c_row[f], dw3[f * 256 + t], s);
        u1[t] = fmaxf(s + db3[t], 0.f);
    }
    if (t < 64) cbT[t * 64 + k] = c_row[t];
    if (t == 0) cnorm[k] = np_sumsq64(&cb[k * 64]);
    __syncthreads();
    {
        float s = 0.f;
        for (int f = 0; f < 256; ++f) s = fmaf(u1[f], dw4[f * 256 + t], s);
        u2[t] = fmaxf(s + db4[t], 0.f);
    }
    __syncthreads();
    if (t < 120) {
        float o = 0.f;
        for (int f = 0; f < 256; ++f) o = fmaf(u2[f], dw5[f * 120 + t], o);
        s_tab[k * 120 + t] = o + db5[t];
    }
}

// ---------------------------------------------------------------------------
// P2: pack weights into MFMA B-frag layout (hi/lo bf16) + W4 + cn2.
// grid 256 x 512.  [validated round 16]
// ---------------------------------------------------------------------------
__global__ __launch_bounds__(512)
void vq_pack(const float* __restrict__ w1, const float* __restrict__ w2,
             const float* __restrict__ ew3, const float* __restrict__ cb,
             const float* __restrict__ eb3,
             unsigned short* __restrict__ pw1, unsigned short* __restrict__ pw2,
             unsigned short* __restrict__ pe3, unsigned short* __restrict__ pw4,
             float* __restrict__ cn2, int* __restrict__ flag_count)
{
    const int t = threadIdx.x;
    int f = blockIdx.x;
    if (f == 0 && t == 0) *flag_count = 0;

    const int lane = t >> 3, j = t & 7;
    float a;
    unsigned short* dst;
    int nt, ks, KSN;

    if (f < 224) {
        const float* src; int srcK, ld;
        if (f < 64)       { src = w1;  dst = pw1; KSN = 4; nt = f >> 2;  ks = f & 3; srcK = 120; ld = 256; }
        else if (f < 192) { f -= 64;  src = w2;  dst = pw2; KSN = 8; nt = f >> 3; ks = f & 7; srcK = 256; ld = 256; }
        else              { f -= 192; src = ew3; dst = pe3; KSN = 8; nt = f >> 3; ks = f & 7; srcK = 256; ld = 64; }
        const int k = ks * 32 + (lane >> 4) * 8 + j;
        const int n = nt * 16 + (lane & 15);
        a = (k < srcK) ? src[k * ld + n] : 0.f;
    } else {
        // W4[k][n] = sum_d ew3[k][d] * cb[n][d]   (k<256, n<64)
        int g = f - 224;
        dst = pw4; KSN = 8; nt = g >> 3; ks = g & 7;
        const int k = ks * 32 + (lane >> 4) * 8 + j;
        const int n = nt * 16 + (lane & 15);
        float s = 0.f;
        const float* er = ew3 + k * 64;
        const float* cr = cb + n * 64;
        for (int d = 0; d < 64; ++d) s = fmaf(er[d], cr[d], s);
        a = s;
        if (g == 0 && t < 64) {
            float ss = 0.f, e2 = 0.f;
            const float* c = cb + t * 64;
            for (int d = 0; d < 64; ++d) { ss = fmaf(c[d], c[d], ss); e2 = fmaf(eb3[d], c[d], e2); }
            cn2[t] = ss - 2.f * e2;
        }
    }

    unsigned short h, l;
    splitbf(a, h, l);
    const int base = (nt * KSN + ks) * 2 * 512;
    dst[base + t] = h;
    dst[base + 512 + t] = l;
}

// ---------------------------------------------------------------------------
// Fast kernel: 32 rows/block, 512 threads (8 waves), 32KB LDS, (512,4).
// G1/G2 [r15 proven]: wave w -> all 32 rows (2 rt), cols [w*32,+32) (2 ct).
// G3+G4 fused [r16 validated]: wave w -> rows (w&1)*16, cols (w>>1)*16;
// z = h2@ew3 + eb3 ; dist = cn2 - 2*(h2@W4) read directly from h2 planes.
// ---------------------------------------------------------------------------
__global__ __launch_bounds__(512, 4)
void vq_fast(const float* __restrict__ x,
             const float* __restrict__ b1, const float* __restrict__ b2,
             const float* __restrict__ eb3, const float* __restrict__ cb,
             const float* __restrict__ s_tab, const float* __restrict__ cn2,
             const unsigned short* __restrict__ pw1, const unsigned short* __restrict__ pw2,
             const unsigned short* __restrict__ pe3, const unsigned short* __restrict__ pw4,
             int* __restrict__ flag_count, int* __restrict__ flag_list,
             float* __restrict__ out)
{
    __shared__ __align__(16) unsigned char smem[32768];
    unsigned short* ph = (unsigned short*)smem;             // hi plane [32][256] swz
    unsigned short* pl = (unsigned short*)(smem + 16384);   // lo plane [32][256] swz
    float*          dm = (float*)smem;                      // dmat [32][68] (aliased)
    int*          idxs = (int*)(smem + 8704);               // [32]          (aliased)

    const int t = threadIdx.x;
    const int w = t >> 6, l = t & 63;
    const int lr = l & 15;
    const int grow0 = blockIdx.x * 32;

    // ---- stage x -> hi/lo planes (swizzled; cols 0..119, pad 120..127 = 0)
    {
        const float* xb = x + (size_t)grow0 * 120;
        unsigned* ph32 = (unsigned*)ph;
        unsigned* pl32 = (unsigned*)pl;
#pragma unroll
        for (int i = 0; i < 4; ++i) {
            int p = t + 512 * i;             // pair index 0..2047
            if (p < 1920) {
                int row = p / 60, c2 = p - row * 60;
                float2 v = *(const float2*)&xb[row * 120 + c2 * 2];
                unsigned u0 = __float_as_uint(v.x);
                unsigned u1 = __float_as_uint(v.y);
                unsigned h0u = u0 & 0xffff0000u;
                unsigned h1u = u1 & 0xffff0000u;
                float d0 = v.x - __uint_as_float(h0u);
                float d1 = v.y - __uint_as_float(h1u);
                int o32 = row * 128 + ((((c2 >> 2) ^ (row & 7))) << 2) + (c2 & 3);
                ph32[o32] = (u0 >> 16) | h1u;
                pl32[o32] = (__float_as_uint(d0) >> 16) | (__float_as_uint(d1) & 0xffff0000u);
            }
        }
        if (t < 128) {
            int row = t >> 2, c2 = 60 + (t & 3);
            int o32 = row * 128 + ((((c2 >> 2) ^ (row & 7))) << 2) + (c2 & 3);
            ph32[o32] = 0u;
            pl32[o32] = 0u;
        }
    }
    __syncthreads();

    // ================= GEMM1: h1 = relu(x @ w1 + b1), K=128(pad) ============
    {
        f32x4 acc[2][2];
#pragma unroll
        for (int a = 0; a < 2; ++a)
#pragma unroll
            for (int b = 0; b < 2; ++b) acc[a][b] = (f32x4)0.f;

#pragma unroll
        for (int ks = 0; ks < 4; ++ks) {
            const int kb = ks * 32 + (l >> 4) * 8;
            s16x8 ah[2], al[2];
#pragma unroll
            for (int rt = 0; rt < 2; ++rt) {
                const int ro = swz(rt * 16 + lr, kb);
                ah[rt] = *(const s16x8*)&ph[ro];
                al[rt] = *(const s16x8*)&pl[ro];
            }
            s16x8 bh[2], bl[2];
#pragma unroll
            for (int ct = 0; ct < 2; ++ct) {
                const unsigned short* pb = pw1 + ((w * 2 + ct) * 4 + ks) * 1024 + l * 8;
                bh[ct] = *(const s16x8*)pb;
                bl[ct] = *(const s16x8*)(pb + 512);
            }
            __builtin_amdgcn_s_setprio(1);
#pragma unroll
            for (int ct = 0; ct < 2; ++ct)
#pragma unroll
                for (int rt = 0; rt < 2; ++rt) {
                    acc[rt][ct] = __builtin_amdgcn_mfma_f32_16x16x32_bf16(ah[rt], bh[ct], acc[rt][ct], 0, 0, 0);
                    acc[rt][ct] = __builtin_amdgcn_mfma_f32_16x16x32_bf16(ah[rt], bl[ct], acc[rt][ct], 0, 0, 0);
                    acc[rt][ct] = __builtin_amdgcn_mfma_f32_16x16x32_bf16(al[rt], bh[ct], acc[rt][ct], 0, 0, 0);
                }
            __builtin_amdgcn_s_setprio(0);
        }
        __syncthreads();
#pragma unroll
        for (int ct = 0; ct < 2; ++ct) {
            const int col = w * 32 + ct * 16 + lr;
            const float bb = b1[col];
#pragma unroll
            for (int rt = 0; rt < 2; ++rt)
#pragma unroll
                for (int r = 0; r < 4; ++r) {
                    float v = fmaxf(acc[rt][ct][r] + bb, 0.f);
                    unsigned short h, s;
                    splitbf_t(v, h, s);
                    const int row = rt * 16 + (l >> 4) * 4 + r;
                    const int o = swz(row, col);
                    ph[o] = h;
                    pl[o] = s;
                }
        }
    }
    __syncthreads();

    // ================= GEMM2: h2 = relu(h1 @ w2 + b2), K=256 ================
    {
        f32x4 acc[2][2];
#pragma unroll
        for (int a = 0; a < 2; ++a)
#pragma unroll
            for (int b = 0; b < 2; ++b) acc[a][b] = (f32x4)0.f;

#pragma unroll
        for (int ks = 0; ks < 8; ++ks) {
            const int kb = ks * 32 + (l >> 4) * 8;
            s16x8 ah[2], al[2];
#pragma unroll
            for (int rt = 0; rt < 2; ++rt) {
                const int ro = swz(rt * 16 + lr, kb);
                ah[rt] = *(const s16x8*)&ph[ro];
                al[rt] = *(const s16x8*)&pl[ro];
            }
            s16x8 bh[2], bl[2];
#pragma unroll
            for (int ct = 0; ct < 2; ++ct) {
                const unsigned short* pb = pw2 + ((w * 2 + ct) * 8 + ks) * 1024 + l * 8;
                bh[ct] = *(const s16x8*)pb;
                bl[ct] = *(const s16x8*)(pb + 512);
            }
            __builtin_amdgcn_s_setprio(1);
#pragma unroll
            for (int ct = 0; ct < 2; ++ct)
#pragma unroll
                for (int rt = 0; rt < 2; ++rt) {
                    acc[rt][ct] = __builtin_amdgcn_mfma_f32_16x16x32_bf16(ah[rt], bh[ct], acc[rt][ct], 0, 0, 0);
                    acc[rt][ct] = __builtin_amdgcn_mfma_f32_16x16x32_bf16(ah[rt], bl[ct], acc[rt][ct], 0, 0, 0);
                    acc[rt][ct] = __builtin_amdgcn_mfma_f32_16x16x32_bf16(al[rt], bh[ct], acc[rt][ct], 0, 0, 0);
                }
            __builtin_amdgcn_s_setprio(0);
        }
        __syncthreads();
#pragma unroll
        for (int ct = 0; ct < 2; ++ct) {
            const int col = w * 32 + ct * 16 + lr;
            const float bb = b2[col];
#pragma unroll
            for (int rt = 0; rt < 2; ++rt)
#pragma unroll
                for (int r = 0; r < 4; ++r) {
                    float v = fmaxf(acc[rt][ct][r] + bb, 0.f);
                    unsigned short h, s;
                    splitbf_t(v, h, s);
                    const int row = rt * 16 + (l >> 4) * 4 + r;
                    const int o = swz(row, col);
                    ph[o] = h;
                    pl[o] = s;
                }
        }
    }
    __syncthreads();

    // ===== G3+G4 fused: z = h2@ew3 + eb3 ; dist = cn2 - 2*(h2@W4), K=256 ====
    const int wrow = w & 1, wcol = w >> 1;
    const int rA = wrow * 16 + lr;
    {
        f32x4 a3 = (f32x4)0.f;
        f32x4 a4 = (f32x4)0.f;

#pragma unroll
        for (int ks = 0; ks < 8; ++ks) {
            const int kb = ks * 32 + (l >> 4) * 8;
            const int ro = swz(rA, kb);
            s16x8 ah = *(const s16x8*)&ph[ro];
            s16x8 al = *(const s16x8*)&pl[ro];
            const unsigned short* pb3 = pe3 + (wcol * 8 + ks) * 1024 + l * 8;
            const unsigned short* pb4 = pw4 + (wcol * 8 + ks) * 1024 + l * 8;
            s16x8 bh3 = *(const s16x8*)pb3;
            s16x8 bl3 = *(const s16x8*)(pb3 + 512);
            s16x8 bh4 = *(const s16x8*)pb4;
            s16x8 bl4 = *(const s16x8*)(pb4 + 512);
            __builtin_amdgcn_s_setprio(1);
            a3 = __builtin_amdgcn_mfma_f32_16x16x32_bf16(ah, bh3, a3, 0, 0, 0);
            a3 = __builtin_amdgcn_mfma_f32_16x16x32_bf16(ah, bl3, a3, 0, 0, 0);
            a3 = __builtin_amdgcn_mfma_f32_16x16x32_bf16(al, bh3, a3, 0, 0, 0);
            a4 = __builtin_amdgcn_mfma_f32_16x16x32_bf16(ah, bh4, a4, 0, 0, 0);
            a4 = __builtin_amdgcn_mfma_f32_16x16x32_bf16(ah, bl4, a4, 0, 0, 0);
            a4 = __builtin_amdgcn_mfma_f32_16x16x32_bf16(al, bh4, a4, 0, 0, 0);
            __builtin_amdgcn_s_setprio(0);
        }
        __syncthreads();   // all plane reads done -> dm alias region usable

        const int col = wcol * 16 + lr;
        const float eb = eb3[col];
        const float cn = cn2[col];
#pragma unroll
        for (int r = 0; r < 4; ++r) {
            const int row = wrow * 16 + (l >> 4) * 4 + r;
            out[ZB + (size_t)(grow0 + row) * 64 + col] = a3[r] + eb;
            dm[row * 68 + col] = cn - 2.f * a4[r];
        }
    }
    __syncthreads();

    // ===== per-row argmin + gap flag =======================================
    if (t < 32) {
        const float* dr = dm + t * 68;
        float best = dr[0], sec = 3.4e38f;
        int bi = 0;
        for (int j = 1; j < 64; ++j) {
            float v = dr[j];
            if (v < best) { sec = best; best = v; bi = j; }
            else if (v < sec) sec = v;
        }
        idxs[t] = bi;
        out[AB + grow0 + t] = (float)bi;
        if (sec - best < THR) {
            int p = atomicAdd(flag_count, 1);
            if (p < B_TOTAL) flag_list[p] = grow0 + t;
        }
    }
    __syncthreads();

    // ===== gathers: emb + s_hat ============================================
#pragma unroll
    for (int i = 0; i < 4; ++i) {
        int p = t + 512 * i;              // 0..2047
        int row = p >> 6, c = p & 63;
        out[EB + (size_t)blockIdx.x * 2048 + p] = cb[idxs[row] * 64 + c];
    }
#pragma unroll
    for (int i = 0; i < 8; ++i) {
        int p = t + 512 * i;              // 0..4095
        if (p < 3840) {
            int row = p / 120, c = p - row * 120;
            out[(size_t)blockIdx.x * 3840 + p] = s_tab[idxs[row] * 120 + c];
        }
    }
}

// ---------------------------------------------------------------------------
// Exact fallback: np-exact math over flagged rows, 16 rows/block, grid 1024.
// [proven round 9 verbatim]
// ---------------------------------------------------------------------------
__global__ __launch_bounds__(256)
void vq_exact(const float* __restrict__ x,
              const float* __restrict__ w1, const float* __restrict__ b1,
              const float* __restrict__ w2, const float* __restrict__ b2,
              const float* __restrict__ ew3, const float* __restrict__ eb3,
              const float* __restrict__ cb,
              const float* __restrict__ s_tab,
              const float* __restrict__ cbT, const float* __restrict__ cnorm,
              const int* __restrict__ flag_count, const int* __restrict__ flag_list,
              float* __restrict__ out)
{
    __shared__ float act[256 * 18];
    __shared__ float zrm[16 * 68];
    __shared__ float dmr[16 * 68];
    __shared__ float A_lds[16];
    __shared__ int   idxs[16];
    __shared__ int   rl[16];

    const int t = threadIdx.x;
    int count = *flag_count;
    if (count > B_TOTAL) count = B_TOTAL;

    const int tx = t & 31;
    const int ty = t >> 5;
    const int r0 = ty * 2;
    const int c0 = tx * 8;
    const int c0d = tx * 2;

    for (int base = blockIdx.x * 16; base < count; base += 1024 * 16) {
        if (t < 16) {
            int li = base + t;
            rl[t] = flag_list[li < count ? li : count - 1];
        }
        __syncthreads();

        for (int i = 0; i < 8; ++i) {
            int p = t + 256 * i;
            if (p < 1920) {
                int r = p / 120;
                int c = p - r * 120;
                act[c * 18 + r] = x[(size_t)rl[r] * 120 + c];
            }
        }
        __syncthreads();

        // GEMM1: K=120
        {
            float acc[2][8];
#pragma unroll
            for (int i = 0; i < 2; ++i)
#pragma unroll
                for (int c = 0; c < 8; ++c) acc[i][c] = 0.f;
#pragma unroll 2
            for (int k = 0; k < 120; ++k) {
                const float2 av = *(const float2*)&act[k * 18 + r0];
                const float4 wv0 = *(const float4*)&w1[k * 256 + c0];
                const float4 wv1 = *(const float4*)&w1[k * 256 + c0 + 4];
                const float a[2] = {av.x, av.y};
                const float wv[8] = {wv0.x, wv0.y, wv0.z, wv0.w, wv1.x, wv1.y, wv1.z, wv1.w};
#pragma unroll
                for (int i = 0; i < 2; ++i)
#pragma unroll
                    for (int c = 0; c < 8; ++c) acc[i][c] = fmaf(a[i], wv[c], acc[i][c]);
            }
            __syncthreads();
            const float4 bv0 = *(const float4*)&b1[c0];
            const float4 bv1 = *(const float4*)&b1[c0 + 4];
            const float bb[8] = {bv0.x, bv0.y, bv0.z, bv0.w, bv1.x, bv1.y, bv1.z, bv1.w};
#pragma unroll
            for (int c = 0; c < 8; ++c)
#pragma unroll
                for (int i = 0; i < 2; ++i)
                    act[(c0 + c) * 18 + r0 + i] = fmaxf(acc[i][c] + bb[c], 0.f);
        }
        __syncthreads();

        // GEMM2: K=256
        {
            float acc[2][8];
#pragma unroll
            for (int i = 0; i < 2; ++i)
#pragma unroll
                for (int c = 0; c < 8; ++c) acc[i][c] = 0.f;
#pragma unroll 2
            for (int k = 0; k < 256; ++k) {
                const float2 av = *(const float2*)&act[k * 18 + r0];
                const float4 wv0 = *(const float4*)&w2[k * 256 + c0];
                const float4 wv1 = *(const float4*)&w2[k * 256 + c0 + 4];
                const float a[2] = {av.x, av.y};
                const float wv[8] = {wv0.x, wv0.y, wv0.z, wv0.w, wv1.x, wv1.y, wv1.z, wv1.w};
#pragma unroll
                for (int i = 0; i < 2; ++i)
#pragma unroll
                    for (int c = 0; c < 8; ++c) acc[i][c] = fmaf(a[i], wv[c], acc[i][c]);
            }
            __syncthreads();
            const float4 bv0 = *(const float4*)&b2[c0];
            const float4 bv1 = *(const float4*)&b2[c0 + 4];
            const float bb[8] = {bv0.x, bv0.y, bv0.z, bv0.w, bv1.x, bv1.y, bv1.z, bv1.w};
#pragma unroll
            for (int c = 0; c < 8; ++c)
#pragma unroll
                for (int i = 0; i < 2; ++i)
                    act[(c0 + c) * 18 + r0 + i] = fmaxf(acc[i][c] + bb[c], 0.f);
        }
        __syncthreads();

        // GEMM3: K=256, 64 cols
        {
            float acc2[2][2];
#pragma unroll
            for (int i = 0; i < 2; ++i) { acc2[i][0] = 0.f; acc2[i][1] = 0.f; }
#pragma unroll 2
            for (int k = 0; k < 256; ++k) {
                const float2 av = *(const float2*)&act[k * 18 + r0];
                const float2 wv = *(const float2*)&ew3[k * 64 + c0d];
#pragma unroll
                for (int i = 0; i < 2; ++i) {
                    float a = (i == 0) ? av.x : av.y;
                    acc2[i][0] = fmaf(a, wv.x, acc2[i][0]);
                    acc2[i][1] = fmaf(a, wv.y, acc2[i][1]);
                }
            }
            __syncthreads();
            const float2 bv = *(const float2*)&eb3[c0d];
#pragma unroll
            for (int i = 0; i < 2; ++i) {
                float z0 = acc2[i][0] + bv.x;
                float z1 = acc2[i][1] + bv.y;
                act[(c0d + 0) * 18 + r0 + i] = z0;
                act[(c0d + 1) * 18 + r0 + i] = z1;
                zrm[(r0 + i) * 68 + c0d]     = z0;
                zrm[(r0 + i) * 68 + c0d + 1] = z1;
            }
        }
        __syncthreads();

        if (t < 16) A_lds[t] = np_sumsq64(&zrm[t * 68]);
        __syncthreads();

        {
            float acc3[2][2];
#pragma unroll
            for (int i = 0; i < 2; ++i) { acc3[i][0] = 0.f; acc3[i][1] = 0.f; }
#pragma unroll 2
            for (int k = 0; k < 64; ++k) {
                const float2 av = *(const float2*)&act[k * 18 + r0];
                const float2 wv = *(const float2*)&cbT[k * 64 + c0d];
#pragma unroll
                for (int i = 0; i < 2; ++i) {
                    float a = (i == 0) ? av.x : av.y;
                    acc3[i][0] = fmaf(a, wv.x, acc3[i][0]);
                    acc3[i][1] = fmaf(a, wv.y, acc3[i][1]);
                }
            }
            const float cn0 = cnorm[c0d], cn1 = cnorm[c0d + 1];
#pragma unroll
            for (int i = 0; i < 2; ++i) {
                float g0 = 2.0f * acc3[i][0];  asm volatile("" : "+v"(g0));
                float g1 = 2.0f * acc3[i][1];  asm volatile("" : "+v"(g1));
                const float Ar = A_lds[r0 + i];
                dmr[(r0 + i) * 68 + c0d]     = (Ar - g0) + cn0;
                dmr[(r0 + i) * 68 + c0d + 1] = (Ar - g1) + cn1;
            }
        }
        __syncthreads();

        if (t < 16) {
            const float* dr = &dmr[t * 68];
            float best = dr[0];
            int bi = 0;
            for (int c = 1; c < 64; ++c) {
                float v = dr[c];
                if (v < best) { best = v; bi = c; }
            }
            idxs[t] = bi;
            out[AB + rl[t]] = (float)bi;
        }
        __syncthreads();

        {
            const int r = t >> 4, q = t & 15;
            *(float4*)(out + ZB + (size_t)rl[r] * 64 + q * 4) = *(const float4*)&zrm[r * 68 + q * 4];
        }
        {
            const int r = t >> 4, q = t & 15;
            *(float4*)(out + EB + (size_t)rl[r] * 64 + q * 4) = *(const float4*)(cb + idxs[r] * 64 + q * 4);
        }
        for (int i = 0; i < 8; ++i) {
            int p = t + 256 * i;
            if (p < 1920) {
                int r = p / 120;
                int c = p - r * 120;
                out[(size_t)rl[r] * 120 + c] = s_tab[idxs[r] * 120 + c];
            }
        }
        __syncthreads();
    }
}

// ---------------------------------------------------------------------------
extern "C" void kernel_launch(void* const* d_in, const int* in_sizes, int n_in,
                              void* d_out, int out_size, void* d_ws, size_t ws_size,
                              hipStream_t stream)
{
    const float* x   = (const float*)d_in[0];
    const float* w1  = (const float*)d_in[1];
    const float* b1  = (const float*)d_in[2];
    const float* w2  = (const float*)d_in[3];
    const float* b2  = (const float*)d_in[4];
    const float* ew3 = (const float*)d_in[5];
    const float* eb3 = (const float*)d_in[6];
    const float* cb  = (const float*)d_in[7];
    const float* dw3 = (const float*)d_in[8];
    const float* db3 = (const float*)d_in[9];
    const float* dw4 = (const float*)d_in[10];
    const float* db4 = (const float*)d_in[11];
    const float* dw5 = (const float*)d_in[12];
    const float* db5 = (const float*)d_in[13];

    float* out = (float*)d_out;
    char* ws = (char*)d_ws;
    float* s_tab = (float*)(ws + WS_STAB);
    float* cbT   = (float*)(ws + WS_CBT);
    float* cnorm = (float*)(ws + WS_CNORM);
    int*   fcnt  = (int*)(ws + WS_COUNT);
    int*   flist = (int*)(ws + WS_LIST);
    unsigned short* pw1 = (unsigned short*)(ws + WS_PKW1);
    unsigned short* pw2 = (unsigned short*)(ws + WS_PKW2);
    unsigned short* pe3 = (unsigned short*)(ws + WS_PKE3);
    unsigned short* pw4 = (unsigned short*)(ws + WS_PKW4);
    float* cn2 = (float*)(ws + WS_CN2);

    vq_prep<<<64, 256, 0, stream>>>(cb, dw3, db3, dw4, db4, dw5, db5,
                                    s_tab, cbT, cnorm);
    vq_pack<<<256, 512, 0, stream>>>(w1, w2, ew3, cb, eb3,
                                     pw1, pw2, pe3, pw4, cn2, fcnt);
    vq_fast<<<B_TOTAL / 32, 512, 0, stream>>>(x, b1, b2, eb3, cb, s_tab, cn2,
                                              pw1, pw2, pe3, pw4, fcnt, flist, out);
    vq_exact<<<1024, 256, 0, stream>>>(x, w1, b1, w2, b2, ew3, eb3, cb,
                                       s_tab, cbT, cnorm, fcnt, flist, out);
}

// Round 18
// 429.825 us; speedup vs baseline: 1.2548x; 1.1497x over previous
//
#include <hip/hip_runtime.h>

// VQ-VAE fused forward. Output f32 layout:
//   s_hat : [0,          31457280)   B x 120
//   z_e   : [31457280,   48234496)   B x 64
//   emb   : [48234496,   65011712)   B x 64
//   argmin: [65011712,   65273856)   B
//
// MFMA fast path (hi/lo bf16 split, 3 products hh+hl+lh); rows with top-2
// distance gap < THR re-run through the np-exact fp32 path.
// R18: B-traffic-minimal geometry — 64 rows/block, 512 thr, 64KB LDS.
// G1/G2: wave w -> ALL 64 rows x cols [w*32,+32): B read ONCE per block,
// A loaded per-rt (live set ~85 regs, (512,4) spill-free).
// G3+G4: waves 0-3 compute z (pe3), waves 4-7 dist (pw4), one col-tile
// each x 4 row-tiles -> every B-tile read once. L2 B-traffic 5.2GB -> 2.1GB.

#define B_TOTAL 262144
#define THR 0.02f

typedef float  f32x4 __attribute__((ext_vector_type(4)));
typedef short  s16x8 __attribute__((ext_vector_type(8)));

#define ZB ((size_t)B_TOTAL * 120)
#define EB ((size_t)B_TOTAL * 184)
#define AB ((size_t)B_TOTAL * 248)

// ---- ws layout (bytes) ----
#define WS_STAB   0         // f32[64*120]   30720
#define WS_CBT    30720     // f32[64*64]    16384
#define WS_CNORM  47104     // f32[64]         256
#define WS_COUNT  47360     // int             64
#define WS_LIST   47424     // int[262144] 1048576
#define WS_PKW1   1096064   // 131072
#define WS_PKW2   1227136   // 262144
#define WS_PKE3   1489280   // 65536
#define WS_PKW4   1554816   // 65536  (W4 = ew3 @ cbT, packed hi/lo)
#define WS_CN2    1620352   // f32[64] 256

static __device__ __forceinline__ unsigned short f2bf(float x) {
    unsigned int u = __float_as_uint(x);
    return (unsigned short)((u + 0x7fffu + ((u >> 16) & 1u)) >> 16);   // RTNE
}
// RTNE split (pack kernel only — once on weights)
static __device__ __forceinline__ void splitbf(float a, unsigned short& h, unsigned short& s) {
    unsigned hb = __float_as_uint(a) & 0xffff0000u;
    h = (unsigned short)(hb >> 16);
    s = f2bf(a - __uint_as_float(hb));
}
// truncated-lo split (fast kernel): 4 VALU ops, err <= 2^-17 * |a|
static __device__ __forceinline__ void splitbf_t(float a, unsigned short& h, unsigned short& s) {
    unsigned u = __float_as_uint(a);
    h = (unsigned short)(u >> 16);
    float d = a - __uint_as_float(u & 0xffff0000u);
    s = (unsigned short)(__float_as_uint(d) >> 16);
}
static __device__ __forceinline__ float sqnc(float v) {
    float s = v * v;
    asm volatile("" : "+v"(s));
    return s;
}
static __device__ __forceinline__ float np_sumsq64(const float* a) {
    float r8[8];
#pragma unroll
    for (int j = 0; j < 8; ++j) r8[j] = sqnc(a[j]);
#pragma unroll
    for (int i = 8; i < 64; i += 8)
#pragma unroll
        for (int j = 0; j < 8; ++j) r8[j] += sqnc(a[i + j]);
    return ((r8[0] + r8[1]) + (r8[2] + r8[3])) + ((r8[4] + r8[5]) + (r8[6] + r8[7]));
}

// swizzled short-index within a [64][256]-short plane (16B-granule XOR)
static __device__ __forceinline__ int swz(int row, int col) {
    return row * 256 + ((((col >> 3) ^ (row & 7))) << 3) + (col & 7);
}

// ---------------------------------------------------------------------------
// P1: decode tables (np-exact). grid 64 x 256.  [proven]
// ---------------------------------------------------------------------------
__global__ __launch_bounds__(256)
void vq_prep(const float* __restrict__ cb,
             const float* __restrict__ dw3, const float* __restrict__ db3,
             const float* __restrict__ dw4, const float* __restrict__ db4,
             const float* __restrict__ dw5, const float* __restrict__ db5,
             float* __restrict__ s_tab, float* __restrict__ cbT, float* __restrict__ cnorm)
{
    __shared__ float c_row[64];
    __shared__ float u1[256];
    __shared__ float u2[256];
    const int k = blockIdx.x;
    const int t = threadIdx.x;

    if (t < 64) c_row[t] = cb[k * 64 + t];
    __syncthreads();
    {
        float s = 0.f;
        for (int f = 0; f < 64; ++f) s = fmaf(c_row[f], dw3[f * 256 + t], s);
        u1[t] = fmaxf(s + db3[t], 0.f);
    }
    if (t < 64) cbT[t * 64 + k] = c_row[t];
    if (t == 0) cnorm[k] = np_sumsq64(&cb[k * 64]);
    __syncthreads();
    {
        float s = 0.f;
        for (int f = 0; f < 256; ++f) s = fmaf(u1[f], dw4[f * 256 + t], s);
        u2[t] = fmaxf(s + db4[t], 0.f);
    }
    __syncthreads();
    if (t < 120) {
        float o = 0.f;
        for (int f = 0; f < 256; ++f) o = fmaf(u2[f], dw5[f * 120 + t], o);
        s_tab[k * 120 + t] = o + db5[t];
    }
}

// ---------------------------------------------------------------------------
// P2: pack weights into MFMA B-frag layout (hi/lo bf16) + W4 + cn2.
// grid 256 x 512.  [validated round 16]
// ---------------------------------------------------------------------------
__global__ __launch_bounds__(512)
void vq_pack(const float* __restrict__ w1, const float* __restrict__ w2,
             const float* __restrict__ ew3, const float* __restrict__ cb,
             const float* __restrict__ eb3,
             unsigned short* __restrict__ pw1, unsigned short* __restrict__ pw2,
             unsigned short* __restrict__ pe3, unsigned short* __restrict__ pw4,
             float* __restrict__ cn2, int* __restrict__ flag_count)
{
    const int t = threadIdx.x;
    int f = blockIdx.x;
    if (f == 0 && t == 0) *flag_count = 0;

    const int lane = t >> 3, j = t & 7;
    float a;
    unsigned short* dst;
    int nt, ks, KSN;

    if (f < 224) {
        const float* src; int srcK, ld;
        if (f < 64)       { src = w1;  dst = pw1; KSN = 4; nt = f >> 2;  ks = f & 3; srcK = 120; ld = 256; }
        else if (f < 192) { f -= 64;  src = w2;  dst = pw2; KSN = 8; nt = f >> 3; ks = f & 7; srcK = 256; ld = 256; }
        else              { f -= 192; src = ew3; dst = pe3; KSN = 8; nt = f >> 3; ks = f & 7; srcK = 256; ld = 64; }
        const int k = ks * 32 + (lane >> 4) * 8 + j;
        const int n = nt * 16 + (lane & 15);
        a = (k < srcK) ? src[k * ld + n] : 0.f;
    } else {
        // W4[k][n] = sum_d ew3[k][d] * cb[n][d]   (k<256, n<64)
        int g = f - 224;
        dst = pw4; KSN = 8; nt = g >> 3; ks = g & 7;
        const int k = ks * 32 + (lane >> 4) * 8 + j;
        const int n = nt * 16 + (lane & 15);
        float s = 0.f;
        const float* er = ew3 + k * 64;
        const float* cr = cb + n * 64;
        for (int d = 0; d < 64; ++d) s = fmaf(er[d], cr[d], s);
        a = s;
        if (g == 0 && t < 64) {
            float ss = 0.f, e2 = 0.f;
            const float* c = cb + t * 64;
            for (int d = 0; d < 64; ++d) { ss = fmaf(c[d], c[d], ss); e2 = fmaf(eb3[d], c[d], e2); }
            cn2[t] = ss - 2.f * e2;
        }
    }

    unsigned short h, l;
    splitbf(a, h, l);
    const int base = (nt * KSN + ks) * 2 * 512;
    dst[base + t] = h;
    dst[base + 512 + t] = l;
}

// ---------------------------------------------------------------------------
// Fast kernel: 64 rows/block, 512 threads (8 waves), 64KB LDS, (512,4).
// G1/G2: wave w -> ALL 64 rows (4 rt), cols [w*32,+32) (2 ct); B read once,
// A loaded per-rt inside the loop.
// G3+G4: mat = w>>2 (0 -> z via pe3, 1 -> dist via pw4), col-tile = w&3,
// all 4 row-tiles -> a[4]; every B-tile read once per block.
// ---------------------------------------------------------------------------
__global__ __launch_bounds__(512, 4)
void vq_fast(const float* __restrict__ x,
             const float* __restrict__ b1, const float* __restrict__ b2,
             const float* __restrict__ eb3, const float* __restrict__ cb,
             const float* __restrict__ s_tab, const float* __restrict__ cn2,
             const unsigned short* __restrict__ pw1, const unsigned short* __restrict__ pw2,
             const unsigned short* __restrict__ pe3, const unsigned short* __restrict__ pw4,
             int* __restrict__ flag_count, int* __restrict__ flag_list,
             float* __restrict__ out)
{
    __shared__ __align__(16) unsigned char smem[65536];
    unsigned short* ph = (unsigned short*)smem;             // hi plane [64][256] swz
    unsigned short* pl = (unsigned short*)(smem + 32768);   // lo plane [64][256] swz
    float*          dm = (float*)smem;                      // dmat [64][68] (aliased)
    int*          idxs = (int*)(smem + 17408);              // [64]          (aliased)

    const int t = threadIdx.x;
    const int w = t >> 6, l = t & 63;
    const int lr = l & 15;
    const int grow0 = blockIdx.x * 64;

    // ---- stage x -> hi/lo planes (swizzled; cols 0..119, pad 120..127 = 0)
    {
        const float* xb = x + (size_t)grow0 * 120;
        unsigned* ph32 = (unsigned*)ph;
        unsigned* pl32 = (unsigned*)pl;
#pragma unroll
        for (int i = 0; i < 8; ++i) {
            int p = t + 512 * i;             // pair index 0..4095
            if (p < 3840) {
                int row = p / 60, c2 = p - row * 60;
                float2 v = *(const float2*)&xb[row * 120 + c2 * 2];
                unsigned u0 = __float_as_uint(v.x);
                unsigned u1 = __float_as_uint(v.y);
                unsigned h0u = u0 & 0xffff0000u;
                unsigned h1u = u1 & 0xffff0000u;
                float d0 = v.x - __uint_as_float(h0u);
                float d1 = v.y - __uint_as_float(h1u);
                int o32 = row * 128 + ((((c2 >> 2) ^ (row & 7))) << 2) + (c2 & 3);
                ph32[o32] = (u0 >> 16) | h1u;
                pl32[o32] = (__float_as_uint(d0) >> 16) | (__float_as_uint(d1) & 0xffff0000u);
            }
        }
        if (t < 256) {
            int row = t >> 2, c2 = 60 + (t & 3);
            int o32 = row * 128 + ((((c2 >> 2) ^ (row & 7))) << 2) + (c2 & 3);
            ph32[o32] = 0u;
            pl32[o32] = 0u;
        }
    }
    __syncthreads();

    // ================= GEMM1: h1 = relu(x @ w1 + b1), K=128(pad) ============
    {
        f32x4 acc[4][2];
#pragma unroll
        for (int a = 0; a < 4; ++a)
#pragma unroll
            for (int b = 0; b < 2; ++b) acc[a][b] = (f32x4)0.f;

#pragma unroll
        for (int ks = 0; ks < 4; ++ks) {
            const int kb = ks * 32 + (l >> 4) * 8;
            s16x8 bh[2], bl[2];
#pragma unroll
            for (int ct = 0; ct < 2; ++ct) {
                const unsigned short* pb = pw1 + ((w * 2 + ct) * 4 + ks) * 1024 + l * 8;
                bh[ct] = *(const s16x8*)pb;
                bl[ct] = *(const s16x8*)(pb + 512);
            }
#pragma unroll
            for (int rt = 0; rt < 4; ++rt) {
                const int ro = swz(rt * 16 + lr, kb);
                s16x8 ah = *(const s16x8*)&ph[ro];
                s16x8 al = *(const s16x8*)&pl[ro];
                __builtin_amdgcn_s_setprio(1);
#pragma unroll
                for (int ct = 0; ct < 2; ++ct) {
                    acc[rt][ct] = __builtin_amdgcn_mfma_f32_16x16x32_bf16(ah, bh[ct], acc[rt][ct], 0, 0, 0);
                    acc[rt][ct] = __builtin_amdgcn_mfma_f32_16x16x32_bf16(ah, bl[ct], acc[rt][ct], 0, 0, 0);
                    acc[rt][ct] = __builtin_amdgcn_mfma_f32_16x16x32_bf16(al, bh[ct], acc[rt][ct], 0, 0, 0);
                }
                __builtin_amdgcn_s_setprio(0);
            }
        }
        __syncthreads();
#pragma unroll
        for (int ct = 0; ct < 2; ++ct) {
            const int col = w * 32 + ct * 16 + lr;
            const float bb = b1[col];
#pragma unroll
            for (int rt = 0; rt < 4; ++rt)
#pragma unroll
                for (int r = 0; r < 4; ++r) {
                    float v = fmaxf(acc[rt][ct][r] + bb, 0.f);
                    unsigned short h, s;
                    splitbf_t(v, h, s);
                    const int row = rt * 16 + (l >> 4) * 4 + r;
                    const int o = swz(row, col);
                    ph[o] = h;
                    pl[o] = s;
                }
        }
    }
    __syncthreads();

    // ================= GEMM2: h2 = relu(h1 @ w2 + b2), K=256 ================
    {
        f32x4 acc[4][2];
#pragma unroll
        for (int a = 0; a < 4; ++a)
#pragma unroll
            for (int b = 0; b < 2; ++b) acc[a][b] = (f32x4)0.f;

#pragma unroll
        for (int ks = 0; ks < 8; ++ks) {
            const int kb = ks * 32 + (l >> 4) * 8;
            s16x8 bh[2], bl[2];
#pragma unroll
            for (int ct = 0; ct < 2; ++ct) {
                const unsigned short* pb = pw2 + ((w * 2 + ct) * 8 + ks) * 1024 + l * 8;
                bh[ct] = *(const s16x8*)pb;
                bl[ct] = *(const s16x8*)(pb + 512);
            }
#pragma unroll
            for (int rt = 0; rt < 4; ++rt) {
                const int ro = swz(rt * 16 + lr, kb);
                s16x8 ah = *(const s16x8*)&ph[ro];
                s16x8 al = *(const s16x8*)&pl[ro];
                __builtin_amdgcn_s_setprio(1);
#pragma unroll
                for (int ct = 0; ct < 2; ++ct) {
                    acc[rt][ct] = __builtin_amdgcn_mfma_f32_16x16x32_bf16(ah, bh[ct], acc[rt][ct], 0, 0, 0);
                    acc[rt][ct] = __builtin_amdgcn_mfma_f32_16x16x32_bf16(ah, bl[ct], acc[rt][ct], 0, 0, 0);
                    acc[rt][ct] = __builtin_amdgcn_mfma_f32_16x16x32_bf16(al, bh[ct], acc[rt][ct], 0, 0, 0);
                }
                __builtin_amdgcn_s_setprio(0);
            }
        }
        __syncthreads();
#pragma unroll
        for (int ct = 0; ct < 2; ++ct) {
            const int col = w * 32 + ct * 16 + lr;
            const float bb = b2[col];
#pragma unroll
            for (int rt = 0; rt < 4; ++rt)
#pragma unroll
                for (int r = 0; r < 4; ++r) {
                    float v = fmaxf(acc[rt][ct][r] + bb, 0.f);
                    unsigned short h, s;
                    splitbf_t(v, h, s);
                    const int row = rt * 16 + (l >> 4) * 4 + r;
                    const int o = swz(row, col);
                    ph[o] = h;
                    pl[o] = s;
                }
        }
    }
    __syncthreads();

    // ===== G3+G4 fused, split by wave: mat=w>>2 (0:z/pe3, 1:dist/pw4), ======
    // ===== col-tile ct3=w&3, all 4 row-tiles. B-tiles read once per block. ==
    const int mat = w >> 2;          // 0..1
    const int ct3 = w & 3;           // 0..3
    {
        f32x4 a[4];
#pragma unroll
        for (int rt = 0; rt < 4; ++rt) a[rt] = (f32x4)0.f;
        const unsigned short* pmat = mat ? pw4 : pe3;

#pragma unroll
        for (int ks = 0; ks < 8; ++ks) {
            const int kb = ks * 32 + (l >> 4) * 8;
            const unsigned short* pb = pmat + (ct3 * 8 + ks) * 1024 + l * 8;
            s16x8 bh = *(const s16x8*)pb;
            s16x8 bl = *(const s16x8*)(pb + 512);
#pragma unroll
            for (int rt = 0; rt < 4; ++rt) {
                const int ro = swz(rt * 16 + lr, kb);
                s16x8 ah = *(const s16x8*)&ph[ro];
                s16x8 al = *(const s16x8*)&pl[ro];
                __builtin_amdgcn_s_setprio(1);
                a[rt] = __builtin_amdgcn_mfma_f32_16x16x32_bf16(ah, bh, a[rt], 0, 0, 0);
                a[rt] = __builtin_amdgcn_mfma_f32_16x16x32_bf16(ah, bl, a[rt], 0, 0, 0);
                a[rt] = __builtin_amdgcn_mfma_f32_16x16x32_bf16(al, bh, a[rt], 0, 0, 0);
                __builtin_amdgcn_s_setprio(0);
            }
        }
        __syncthreads();   // all plane reads done -> dm alias region usable

        const int col = ct3 * 16 + lr;
        if (mat == 0) {
            const float eb = eb3[col];
#pragma unroll
            for (int rt = 0; rt < 4; ++rt)
#pragma unroll
                for (int r = 0; r < 4; ++r) {
                    const int row = rt * 16 + (l >> 4) * 4 + r;
                    out[ZB + (size_t)(grow0 + row) * 64 + col] = a[rt][r] + eb;
                }
        } else {
            const float cn = cn2[col];
#pragma unroll
            for (int rt = 0; rt < 4; ++rt)
#pragma unroll
                for (int r = 0; r < 4; ++r) {
                    const int row = rt * 16 + (l >> 4) * 4 + r;
                    dm[row * 68 + col] = cn - 2.f * a[rt][r];
                }
        }
    }
    __syncthreads();

    // ===== per-row argmin + gap flag =======================================
    if (t < 64) {
        const float* dr = dm + t * 68;
        float best = dr[0], sec = 3.4e38f;
        int bi = 0;
        for (int j = 1; j < 64; ++j) {
            float v = dr[j];
            if (v < best) { sec = best; best = v; bi = j; }
            else if (v < sec) sec = v;
        }
        idxs[t] = bi;
        out[AB + grow0 + t] = (float)bi;
        if (sec - best < THR) {
            int p = atomicAdd(flag_count, 1);
            if (p < B_TOTAL) flag_list[p] = grow0 + t;
        }
    }
    __syncthreads();

    // ===== gathers: emb + s_hat ============================================
#pragma unroll
    for (int i = 0; i < 8; ++i) {
        int p = t + 512 * i;              // 0..4095
        int row = p >> 6, c = p & 63;
        out[EB + (size_t)blockIdx.x * 4096 + p] = cb[idxs[row] * 64 + c];
    }
#pragma unroll
    for (int i = 0; i < 15; ++i) {
        int p = t + 512 * i;              // 0..7679
        int row = p / 120, c = p - row * 120;
        out[(size_t)blockIdx.x * 7680 + p] = s_tab[idxs[row] * 120 + c];
    }
}

// ---------------------------------------------------------------------------
// Exact fallback: np-exact math over flagged rows, 16 rows/block, grid 1024.
// [proven round 9 verbatim]
// ---------------------------------------------------------------------------
__global__ __launch_bounds__(256)
void vq_exact(const float* __restrict__ x,
              const float* __restrict__ w1, const float* __restrict__ b1,
              const float* __restrict__ w2, const float* __restrict__ b2,
              const float* __restrict__ ew3, const float* __restrict__ eb3,
              const float* __restrict__ cb,
              const float* __restrict__ s_tab,
              const float* __restrict__ cbT, const float* __restrict__ cnorm,
              const int* __restrict__ flag_count, const int* __restrict__ flag_list,
              float* __restrict__ out)
{
    __shared__ float act[256 * 18];
    __shared__ float zrm[16 * 68];
    __shared__ float dmr[16 * 68];
    __shared__ float A_lds[16];
    __shared__ int   idxs[16];
    __shared__ int   rl[16];

    const int t = threadIdx.x;
    int count = *flag_count;
    if (count > B_TOTAL) count = B_TOTAL;

    const int tx = t & 31;
    const int ty = t >> 5;
    const int r0 = ty * 2;
    const int c0 = tx * 8;
    const int c0d = tx * 2;

    for (int base = blockIdx.x * 16; base < count; base += 1024 * 16) {
        if (t < 16) {
            int li = base + t;
            rl[t] = flag_list[li < count ? li : count - 1];
        }
        __syncthreads();

        for (int i = 0; i < 8; ++i) {
            int p = t + 256 * i;
            if (p < 1920) {
                int r = p / 120;
                int c = p - r * 120;
                act[c * 18 + r] = x[(size_t)rl[r] * 120 + c];
            }
        }
        __syncthreads();

        // GEMM1: K=120
        {
            float acc[2][8];
#pragma unroll
            for (int i = 0; i < 2; ++i)
#pragma unroll
                for (int c = 0; c < 8; ++c) acc[i][c] = 0.f;
#pragma unroll 2
            for (int k = 0; k < 120; ++k) {
                const float2 av = *(const float2*)&act[k * 18 + r0];
                const float4 wv0 = *(const float4*)&w1[k * 256 + c0];
                const float4 wv1 = *(const float4*)&w1[k * 256 + c0 + 4];
                const float a[2] = {av.x, av.y};
                const float wv[8] = {wv0.x, wv0.y, wv0.z, wv0.w, wv1.x, wv1.y, wv1.z, wv1.w};
#pragma unroll
                for (int i = 0; i < 2; ++i)
#pragma unroll
                    for (int c = 0; c < 8; ++c) acc[i][c] = fmaf(a[i], wv[c], acc[i][c]);
            }
            __syncthreads();
            const float4 bv0 = *(const float4*)&b1[c0];
            const float4 bv1 = *(const float4*)&b1[c0 + 4];
            const float bb[8] = {bv0.x, bv0.y, bv0.z, bv0.w, bv1.x, bv1.y, bv1.z, bv1.w};
#pragma unroll
            for (int c = 0; c < 8; ++c)
#pragma unroll
                for (int i = 0; i < 2; ++i)
                    act[(c0 + c) * 18 + r0 + i] = fmaxf(acc[i][c] + bb[c], 0.f);
        }
        __syncthreads();

        // GEMM2: K=256
        {
            float acc[2][8];
#pragma unroll
            for (int i = 0; i < 2; ++i)
#pragma unroll
                for (int c = 0; c < 8; ++c) acc[i][c] = 0.f;
#pragma unroll 2
            for (int k = 0; k < 256; ++k) {
                const float2 av = *(const float2*)&act[k * 18 + r0];
                const float4 wv0 = *(const float4*)&w2[k * 256 + c0];
                const float4 wv1 = *(const float4*)&w2[k * 256 + c0 + 4];
                const float a[2] = {av.x, av.y};
                const float wv[8] = {wv0.x, wv0.y, wv0.z, wv0.w, wv1.x, wv1.y, wv1.z, wv1.w};
#pragma unroll
                for (int i = 0; i < 2; ++i)
#pragma unroll
                    for (int c = 0; c < 8; ++c) acc[i][c] = fmaf(a[i], wv[c], acc[i][c]);
            }
            __syncthreads();
            const float4 bv0 = *(const float4*)&b2[c0];
            const float4 bv1 = *(const float4*)&b2[c0 + 4];
            const float bb[8] = {bv0.x, bv0.y, bv0.z, bv0.w, bv1.x, bv1.y, bv1.z, bv1.w};
#pragma unroll
            for (int c = 0; c < 8; ++c)
#pragma unroll
                for (int i = 0; i < 2; ++i)
                    act[(c0 + c) * 18 + r0 + i] = fmaxf(acc[i][c] + bb[c], 0.f);
        }
        __syncthreads();

        // GEMM3: K=256, 64 cols
        {
            float acc2[2][2];
#pragma unroll
            for (int i = 0; i < 2; ++i) { acc2[i][0] = 0.f; acc2[i][1] = 0.f; }
#pragma unroll 2
            for (int k = 0; k < 256; ++k) {
                const float2 av = *(const float2*)&act[k * 18 + r0];
                const float2 wv = *(const float2*)&ew3[k * 64 + c0d];
#pragma unroll
                for (int i = 0; i < 2; ++i) {
                    float a = (i == 0) ? av.x : av.y;
                    acc2[i][0] = fmaf(a, wv.x, acc2[i][0]);
                    acc2[i][1] = fmaf(a, wv.y, acc2[i][1]);
                }
            }
            __syncthreads();
            const float2 bv = *(const float2*)&eb3[c0d];
#pragma unroll
            for (int i = 0; i < 2; ++i) {
                float z0 = acc2[i][0] + bv.x;
                float z1 = acc2[i][1] + bv.y;
                act[(c0d + 0) * 18 + r0 + i] = z0;
                act[(c0d + 1) * 18 + r0 + i] = z1;
                zrm[(r0 + i) * 68 + c0d]     = z0;
                zrm[(r0 + i) * 68 + c0d + 1] = z1;
            }
        }
        __syncthreads();

        if (t < 16) A_lds[t] = np_sumsq64(&zrm[t * 68]);
        __syncthreads();

        {
            float acc3[2][2];
#pragma unroll
            for (int i = 0; i < 2; ++i) { acc3[i][0] = 0.f; acc3[i][1] = 0.f; }
#pragma unroll 2
            for (int k = 0; k < 64; ++k) {
                const float2 av = *(const float2*)&act[k * 18 + r0];
                const float2 wv = *(const float2*)&cbT[k * 64 + c0d];
#pragma unroll
                for (int i = 0; i < 2; ++i) {
                    float a = (i == 0) ? av.x : av.y;
                    acc3[i][0] = fmaf(a, wv.x, acc3[i][0]);
                    acc3[i][1] = fmaf(a, wv.y, acc3[i][1]);
                }
            }
            const float cn0 = cnorm[c0d], cn1 = cnorm[c0d + 1];
#pragma unroll
            for (int i = 0; i < 2; ++i) {
                float g0 = 2.0f * acc3[i][0];  asm volatile("" : "+v"(g0));
                float g1 = 2.0f * acc3[i][1];  asm volatile("" : "+v"(g1));
                const float Ar = A_lds[r0 + i];
                dmr[(r0 + i) * 68 + c0d]     = (Ar - g0) + cn0;
                dmr[(r0 + i) * 68 + c0d + 1] = (Ar - g1) + cn1;
            }
        }
        __syncthreads();

        if (t < 16) {
            const float* dr = &dmr[t * 68];
            float best = dr[0];
            int bi = 0;
            for (int c = 1; c < 64; ++c) {
                float v = dr[c];
                if (v < best) { best = v; bi = c; }
            }
            idxs[t] = bi;
            out[AB + rl[t]] = (float)bi;
        }
        __syncthreads();

        {
            const int r = t >> 4, q = t & 15;
            *(float4*)(out + ZB + (size_t)rl[r] * 64 + q * 4) = *(const float4*)&zrm[r * 68 + q * 4];
        }
        {
            const int r = t >> 4, q = t & 15;
            *(float4*)(out + EB + (size_t)rl[r] * 64 + q * 4) = *(const float4*)(cb + idxs[r] * 64 + q * 4);
        }
        for (int i = 0; i < 8; ++i) {
            int p = t + 256 * i;
            if (p < 1920) {
                int r = p / 120;
                int c = p - r * 120;
                out[(size_t)rl[r] * 120 + c] = s_tab[idxs[r] * 120 + c];
            }
        }
        __syncthreads();
    }
}

// ---------------------------------------------------------------------------
extern "C" void kernel_launch(void* const* d_in, const int* in_sizes, int n_in,
                              void* d_out, int out_size, void* d_ws, size_t ws_size,
                              hipStream_t stream)
{
    const float* x   = (const float*)d_in[0];
    const float* w1  = (const float*)d_in[1];
    const float* b1  = (const float*)d_in[2];
    const float* w2  = (const float*)d_in[3];
    const float* b2  = (const float*)d_in[4];
    const float* ew3 = (const float*)d_in[5];
    const float* eb3 = (const float*)d_in[6];
    const float* cb  = (const float*)d_in[7];
    const float* dw3 = (const float*)d_in[8];
    const float* db3 = (const float*)d_in[9];
    const float* dw4 = (const float*)d_in[10];
    const float* db4 = (const float*)d_in[11];
    const float* dw5 = (const float*)d_in[12];
    const float* db5 = (const float*)d_in[13];

    float* out = (float*)d_out;
    char* ws = (char*)d_ws;
    float* s_tab = (float*)(ws + WS_STAB);
    float* cbT   = (float*)(ws + WS_CBT);
    float* cnorm = (float*)(ws + WS_CNORM);
    int*   fcnt  = (int*)(ws + WS_COUNT);
    int*   flist = (int*)(ws + WS_LIST);
    unsigned short* pw1 = (unsigned short*)(ws + WS_PKW1);
    unsigned short* pw2 = (unsigned short*)(ws + WS_PKW2);
    unsigned short* pe3 = (unsigned short*)(ws + WS_PKE3);
    unsigned short* pw4 = (unsigned short*)(ws + WS_PKW4);
    float* cn2 = (float*)(ws + WS_CN2);

    vq_prep<<<64, 256, 0, stream>>>(cb, dw3, db3, dw4, db4, dw5, db5,
                                    s_tab, cbT, cnorm);
    vq_pack<<<256, 512, 0, stream>>>(w1, w2, ew3, cb, eb3,
                                     pw1, pw2, pe3, pw4, cn2, fcnt);
    vq_fast<<<B_TOTAL / 64, 512, 0, stream>>>(x, b1, b2, eb3, cb, s_tab, cn2,
                                              pw1, pw2, pe3, pw4, fcnt, flist, out);
    vq_exact<<<1024, 256, 0, stream>>>(x, w1, b1, w2, b2, ew3, eb3, cb,
                                       s_tab, cbT, cnorm, fcnt, flist, out);
}

// Round 19
// 420.797 us; speedup vs baseline: 1.2817x; 1.0215x over previous
//
#include <hip/hip_runtime.h>

// VQ-VAE fused forward. Output f32 layout:
//   s_hat : [0,          31457280)   B x 120
//   z_e   : [31457280,   48234496)   B x 64
//   emb   : [48234496,   65011712)   B x 64
//   argmin: [65011712,   65273856)   B
//
// MFMA fast path (hi/lo bf16 split, 3 products hh+hl+lh); rows with top-2
// distance gap < THR re-run through the np-exact fp32 path.
// R19: r18 geometry (64 rows/block, B-read-once, W4-fused G3G4) with
// __launch_bounds__(512,3) — 170-reg budget kills the marginal spill
// (r18: WRITE 312/FETCH 100 vs clean 255/65; spill also inflates the
// non-fast remainder by ~60us across all prior rounds).

#define B_TOTAL 262144
#define THR 0.02f

typedef float  f32x4 __attribute__((ext_vector_type(4)));
typedef short  s16x8 __attribute__((ext_vector_type(8)));

#define ZB ((size_t)B_TOTAL * 120)
#define EB ((size_t)B_TOTAL * 184)
#define AB ((size_t)B_TOTAL * 248)

// ---- ws layout (bytes) ----
#define WS_STAB   0         // f32[64*120]   30720
#define WS_CBT    30720     // f32[64*64]    16384
#define WS_CNORM  47104     // f32[64]         256
#define WS_COUNT  47360     // int             64
#define WS_LIST   47424     // int[262144] 1048576
#define WS_PKW1   1096064   // 131072
#define WS_PKW2   1227136   // 262144
#define WS_PKE3   1489280   // 65536
#define WS_PKW4   1554816   // 65536  (W4 = ew3 @ cbT, packed hi/lo)
#define WS_CN2    1620352   // f32[64] 256

static __device__ __forceinline__ unsigned short f2bf(float x) {
    unsigned int u = __float_as_uint(x);
    return (unsigned short)((u + 0x7fffu + ((u >> 16) & 1u)) >> 16);   // RTNE
}
// RTNE split (pack kernel only — once on weights)
static __device__ __forceinline__ void splitbf(float a, unsigned short& h, unsigned short& s) {
    unsigned hb = __float_as_uint(a) & 0xffff0000u;
    h = (unsigned short)(hb >> 16);
    s = f2bf(a - __uint_as_float(hb));
}
// truncated-lo split (fast kernel): 4 VALU ops, err <= 2^-17 * |a|
static __device__ __forceinline__ void splitbf_t(float a, unsigned short& h, unsigned short& s) {
    unsigned u = __float_as_uint(a);
    h = (unsigned short)(u >> 16);
    float d = a - __uint_as_float(u & 0xffff0000u);
    s = (unsigned short)(__float_as_uint(d) >> 16);
}
static __device__ __forceinline__ float sqnc(float v) {
    float s = v * v;
    asm volatile("" : "+v"(s));
    return s;
}
static __device__ __forceinline__ float np_sumsq64(const float* a) {
    float r8[8];
#pragma unroll
    for (int j = 0; j < 8; ++j) r8[j] = sqnc(a[j]);
#pragma unroll
    for (int i = 8; i < 64; i += 8)
#pragma unroll
        for (int j = 0; j < 8; ++j) r8[j] += sqnc(a[i + j]);
    return ((r8[0] + r8[1]) + (r8[2] + r8[3])) + ((r8[4] + r8[5]) + (r8[6] + r8[7]));
}

// swizzled short-index within a [64][256]-short plane (16B-granule XOR)
static __device__ __forceinline__ int swz(int row, int col) {
    return row * 256 + ((((col >> 3) ^ (row & 7))) << 3) + (col & 7);
}

// ---------------------------------------------------------------------------
// P1: decode tables (np-exact). grid 64 x 256.  [proven]
// ---------------------------------------------------------------------------
__global__ __launch_bounds__(256)
void vq_prep(const float* __restrict__ cb,
             const float* __restrict__ dw3, const float* __restrict__ db3,
             const float* __restrict__ dw4, const float* __restrict__ db4,
             const float* __restrict__ dw5, const float* __restrict__ db5,
             float* __restrict__ s_tab, float* __restrict__ cbT, float* __restrict__ cnorm)
{
    __shared__ float c_row[64];
    __shared__ float u1[256];
    __shared__ float u2[256];
    const int k = blockIdx.x;
    const int t = threadIdx.x;

    if (t < 64) c_row[t] = cb[k * 64 + t];
    __syncthreads();
    {
        float s = 0.f;
        for (int f = 0; f < 64; ++f) s = fmaf(c_row[f], dw3[f * 256 + t], s);
        u1[t] = fmaxf(s + db3[t], 0.f);
    }
    if (t < 64) cbT[t * 64 + k] = c_row[t];
    if (t == 0) cnorm[k] = np_sumsq64(&cb[k * 64]);
    __syncthreads();
    {
        float s = 0.f;
        for (int f = 0; f < 256; ++f) s = fmaf(u1[f], dw4[f * 256 + t], s);
        u2[t] = fmaxf(s + db4[t], 0.f);
    }
    __syncthreads();
    if (t < 120) {
        float o = 0.f;
        for (int f = 0; f < 256; ++f) o = fmaf(u2[f], dw5[f * 120 + t], o);
        s_tab[k * 120 + t] = o + db5[t];
    }
}

// ---------------------------------------------------------------------------
// P2: pack weights into MFMA B-frag layout (hi/lo bf16) + W4 + cn2.
// grid 256 x 512.  [validated round 16]
// ---------------------------------------------------------------------------
__global__ __launch_bounds__(512)
void vq_pack(const float* __restrict__ w1, const float* __restrict__ w2,
             const float* __restrict__ ew3, const float* __restrict__ cb,
             const float* __restrict__ eb3,
             unsigned short* __restrict__ pw1, unsigned short* __restrict__ pw2,
             unsigned short* __restrict__ pe3, unsigned short* __restrict__ pw4,
             float* __restrict__ cn2, int* __restrict__ flag_count)
{
    const int t = threadIdx.x;
    int f = blockIdx.x;
    if (f == 0 && t == 0) *flag_count = 0;

    const int lane = t >> 3, j = t & 7;
    float a;
    unsigned short* dst;
    int nt, ks, KSN;

    if (f < 224) {
        const float* src; int srcK, ld;
        if (f < 64)       { src = w1;  dst = pw1; KSN = 4; nt = f >> 2;  ks = f & 3; srcK = 120; ld = 256; }
        else if (f < 192) { f -= 64;  src = w2;  dst = pw2; KSN = 8; nt = f >> 3; ks = f & 7; srcK = 256; ld = 256; }
        else              { f -= 192; src = ew3; dst = pe3; KSN = 8; nt = f >> 3; ks = f & 7; srcK = 256; ld = 64; }
        const int k = ks * 32 + (lane >> 4) * 8 + j;
        const int n = nt * 16 + (lane & 15);
        a = (k < srcK) ? src[k * ld + n] : 0.f;
    } else {
        // W4[k][n] = sum_d ew3[k][d] * cb[n][d]   (k<256, n<64)
        int g = f - 224;
        dst = pw4; KSN = 8; nt = g >> 3; ks = g & 7;
        const int k = ks * 32 + (lane >> 4) * 8 + j;
        const int n = nt * 16 + (lane & 15);
        float s = 0.f;
        const float* er = ew3 + k * 64;
        const float* cr = cb + n * 64;
        for (int d = 0; d < 64; ++d) s = fmaf(er[d], cr[d], s);
        a = s;
        if (g == 0 && t < 64) {
            float ss = 0.f, e2 = 0.f;
            const float* c = cb + t * 64;
            for (int d = 0; d < 64; ++d) { ss = fmaf(c[d], c[d], ss); e2 = fmaf(eb3[d], c[d], e2); }
            cn2[t] = ss - 2.f * e2;
        }
    }

    unsigned short h, l;
    splitbf(a, h, l);
    const int base = (nt * KSN + ks) * 2 * 512;
    dst[base + t] = h;
    dst[base + 512 + t] = l;
}

// ---------------------------------------------------------------------------
// Fast kernel: 64 rows/block, 512 threads (8 waves), 64KB LDS, (512,3).
// G1/G2: wave w -> ALL 64 rows (4 rt), cols [w*32,+32) (2 ct); B read once,
// A loaded per-rt inside the loop.
// G3+G4: mat = w>>2 (0 -> z via pe3, 1 -> dist via pw4), col-tile = w&3,
// all 4 row-tiles -> a[4]; every B-tile read once per block.
// ---------------------------------------------------------------------------
__global__ __launch_bounds__(512, 3)
void vq_fast(const float* __restrict__ x,
             const float* __restrict__ b1, const float* __restrict__ b2,
             const float* __restrict__ eb3, const float* __restrict__ cb,
             const float* __restrict__ s_tab, const float* __restrict__ cn2,
             const unsigned short* __restrict__ pw1, const unsigned short* __restrict__ pw2,
             const unsigned short* __restrict__ pe3, const unsigned short* __restrict__ pw4,
             int* __restrict__ flag_count, int* __restrict__ flag_list,
             float* __restrict__ out)
{
    __shared__ __align__(16) unsigned char smem[65536];
    unsigned short* ph = (unsigned short*)smem;             // hi plane [64][256] swz
    unsigned short* pl = (unsigned short*)(smem + 32768);   // lo plane [64][256] swz
    float*          dm = (float*)smem;                      // dmat [64][68] (aliased)
    int*          idxs = (int*)(smem + 17408);              // [64]          (aliased)

    const int t = threadIdx.x;
    const int w = t >> 6, l = t & 63;
    const int lr = l & 15;
    const int grow0 = blockIdx.x * 64;

    // ---- stage x -> hi/lo planes (swizzled; cols 0..119, pad 120..127 = 0)
    {
        const float* xb = x + (size_t)grow0 * 120;
        unsigned* ph32 = (unsigned*)ph;
        unsigned* pl32 = (unsigned*)pl;
#pragma unroll
        for (int i = 0; i < 8; ++i) {
            int p = t + 512 * i;             // pair index 0..4095
            if (p < 3840) {
                int row = p / 60, c2 = p - row * 60;
                float2 v = *(const float2*)&xb[row * 120 + c2 * 2];
                unsigned u0 = __float_as_uint(v.x);
                unsigned u1 = __float_as_uint(v.y);
                unsigned h0u = u0 & 0xffff0000u;
                unsigned h1u = u1 & 0xffff0000u;
                float d0 = v.x - __uint_as_float(h0u);
                float d1 = v.y - __uint_as_float(h1u);
                int o32 = row * 128 + ((((c2 >> 2) ^ (row & 7))) << 2) + (c2 & 3);
                ph32[o32] = (u0 >> 16) | h1u;
                pl32[o32] = (__float_as_uint(d0) >> 16) | (__float_as_uint(d1) & 0xffff0000u);
            }
        }
        if (t < 256) {
            int row = t >> 2, c2 = 60 + (t & 3);
            int o32 = row * 128 + ((((c2 >> 2) ^ (row & 7))) << 2) + (c2 & 3);
            ph32[o32] = 0u;
            pl32[o32] = 0u;
        }
    }
    __syncthreads();

    // ================= GEMM1: h1 = relu(x @ w1 + b1), K=128(pad) ============
    {
        f32x4 acc[4][2];
#pragma unroll
        for (int a = 0; a < 4; ++a)
#pragma unroll
            for (int b = 0; b < 2; ++b) acc[a][b] = (f32x4)0.f;

#pragma unroll
        for (int ks = 0; ks < 4; ++ks) {
            const int kb = ks * 32 + (l >> 4) * 8;
            s16x8 bh[2], bl[2];
#pragma unroll
            for (int ct = 0; ct < 2; ++ct) {
                const unsigned short* pb = pw1 + ((w * 2 + ct) * 4 + ks) * 1024 + l * 8;
                bh[ct] = *(const s16x8*)pb;
                bl[ct] = *(const s16x8*)(pb + 512);
            }
#pragma unroll
            for (int rt = 0; rt < 4; ++rt) {
                const int ro = swz(rt * 16 + lr, kb);
                s16x8 ah = *(const s16x8*)&ph[ro];
                s16x8 al = *(const s16x8*)&pl[ro];
                __builtin_amdgcn_s_setprio(1);
#pragma unroll
                for (int ct = 0; ct < 2; ++ct) {
                    acc[rt][ct] = __builtin_amdgcn_mfma_f32_16x16x32_bf16(ah, bh[ct], acc[rt][ct], 0, 0, 0);
                    acc[rt][ct] = __builtin_amdgcn_mfma_f32_16x16x32_bf16(ah, bl[ct], acc[rt][ct], 0, 0, 0);
                    acc[rt][ct] = __builtin_amdgcn_mfma_f32_16x16x32_bf16(al, bh[ct], acc[rt][ct], 0, 0, 0);
                }
                __builtin_amdgcn_s_setprio(0);
            }
        }
        __syncthreads();
#pragma unroll
        for (int ct = 0; ct < 2; ++ct) {
            const int col = w * 32 + ct * 16 + lr;
            const float bb = b1[col];
#pragma unroll
            for (int rt = 0; rt < 4; ++rt)
#pragma unroll
                for (int r = 0; r < 4; ++r) {
                    float v = fmaxf(acc[rt][ct][r] + bb, 0.f);
                    unsigned short h, s;
                    splitbf_t(v, h, s);
                    const int row = rt * 16 + (l >> 4) * 4 + r;
                    const int o = swz(row, col);
                    ph[o] = h;
                    pl[o] = s;
                }
        }
    }
    __syncthreads();

    // ================= GEMM2: h2 = relu(h1 @ w2 + b2), K=256 ================
    {
        f32x4 acc[4][2];
#pragma unroll
        for (int a = 0; a < 4; ++a)
#pragma unroll
            for (int b = 0; b < 2; ++b) acc[a][b] = (f32x4)0.f;

#pragma unroll
        for (int ks = 0; ks < 8; ++ks) {
            const int kb = ks * 32 + (l >> 4) * 8;
            s16x8 bh[2], bl[2];
#pragma unroll
            for (int ct = 0; ct < 2; ++ct) {
                const unsigned short* pb = pw2 + ((w * 2 + ct) * 8 + ks) * 1024 + l * 8;
                bh[ct] = *(const s16x8*)pb;
                bl[ct] = *(const s16x8*)(pb + 512);
            }
#pragma unroll
            for (int rt = 0; rt < 4; ++rt) {
                const int ro = swz(rt * 16 + lr, kb);
                s16x8 ah = *(const s16x8*)&ph[ro];
                s16x8 al = *(const s16x8*)&pl[ro];
                __builtin_amdgcn_s_setprio(1);
#pragma unroll
                for (int ct = 0; ct < 2; ++ct) {
                    acc[rt][ct] = __builtin_amdgcn_mfma_f32_16x16x32_bf16(ah, bh[ct], acc[rt][ct], 0, 0, 0);
                    acc[rt][ct] = __builtin_amdgcn_mfma_f32_16x16x32_bf16(ah, bl[ct], acc[rt][ct], 0, 0, 0);
                    acc[rt][ct] = __builtin_amdgcn_mfma_f32_16x16x32_bf16(al, bh[ct], acc[rt][ct], 0, 0, 0);
                }
                __builtin_amdgcn_s_setprio(0);
            }
        }
        __syncthreads();
#pragma unroll
        for (int ct = 0; ct < 2; ++ct) {
            const int col = w * 32 + ct * 16 + lr;
            const float bb = b2[col];
#pragma unroll
            for (int rt = 0; rt < 4; ++rt)
#pragma unroll
                for (int r = 0; r < 4; ++r) {
                    float v = fmaxf(acc[rt][ct][r] + bb, 0.f);
                    unsigned short h, s;
                    splitbf_t(v, h, s);
                    const int row = rt * 16 + (l >> 4) * 4 + r;
                    const int o = swz(row, col);
                    ph[o] = h;
                    pl[o] = s;
                }
        }
    }
    __syncthreads();

    // ===== G3+G4 fused, split by wave: mat=w>>2 (0:z/pe3, 1:dist/pw4), ======
    // ===== col-tile ct3=w&3, all 4 row-tiles. B-tiles read once per block. ==
    const int mat = w >> 2;          // 0..1
    const int ct3 = w & 3;           // 0..3
    {
        f32x4 a[4];
#pragma unroll
        for (int rt = 0; rt < 4; ++rt) a[rt] = (f32x4)0.f;
        const unsigned short* pmat = mat ? pw4 : pe3;

#pragma unroll
        for (int ks = 0; ks < 8; ++ks) {
            const int kb = ks * 32 + (l >> 4) * 8;
            const unsigned short* pb = pmat + (ct3 * 8 + ks) * 1024 + l * 8;
            s16x8 bh = *(const s16x8*)pb;
            s16x8 bl = *(const s16x8*)(pb + 512);
#pragma unroll
            for (int rt = 0; rt < 4; ++rt) {
                const int ro = swz(rt * 16 + lr, kb);
                s16x8 ah = *(const s16x8*)&ph[ro];
                s16x8 al = *(const s16x8*)&pl[ro];
                __builtin_amdgcn_s_setprio(1);
                a[rt] = __builtin_amdgcn_mfma_f32_16x16x32_bf16(ah, bh, a[rt], 0, 0, 0);
                a[rt] = __builtin_amdgcn_mfma_f32_16x16x32_bf16(ah, bl, a[rt], 0, 0, 0);
                a[rt] = __builtin_amdgcn_mfma_f32_16x16x32_bf16(al, bh, a[rt], 0, 0, 0);
                __builtin_amdgcn_s_setprio(0);
            }
        }
        __syncthreads();   // all plane reads done -> dm alias region usable

        const int col = ct3 * 16 + lr;
        if (mat == 0) {
            const float eb = eb3[col];
#pragma unroll
            for (int rt = 0; rt < 4; ++rt)
#pragma unroll
                for (int r = 0; r < 4; ++r) {
                    const int row = rt * 16 + (l >> 4) * 4 + r;
                    out[ZB + (size_t)(grow0 + row) * 64 + col] = a[rt][r] + eb;
                }
        } else {
            const float cn = cn2[col];
#pragma unroll
            for (int rt = 0; rt < 4; ++rt)
#pragma unroll
                for (int r = 0; r < 4; ++r) {
                    const int row = rt * 16 + (l >> 4) * 4 + r;
                    dm[row * 68 + col] = cn - 2.f * a[rt][r];
                }
        }
    }
    __syncthreads();

    // ===== per-row argmin + gap flag =======================================
    if (t < 64) {
        const float* dr = dm + t * 68;
        float best = dr[0], sec = 3.4e38f;
        int bi = 0;
        for (int j = 1; j < 64; ++j) {
            float v = dr[j];
            if (v < best) { sec = best; best = v; bi = j; }
            else if (v < sec) sec = v;
        }
        idxs[t] = bi;
        out[AB + grow0 + t] = (float)bi;
        if (sec - best < THR) {
            int p = atomicAdd(flag_count, 1);
            if (p < B_TOTAL) flag_list[p] = grow0 + t;
        }
    }
    __syncthreads();

    // ===== gathers: emb + s_hat ============================================
#pragma unroll
    for (int i = 0; i < 8; ++i) {
        int p = t + 512 * i;              // 0..4095
        int row = p >> 6, c = p & 63;
        out[EB + (size_t)blockIdx.x * 4096 + p] = cb[idxs[row] * 64 + c];
    }
#pragma unroll
    for (int i = 0; i < 15; ++i) {
        int p = t + 512 * i;              // 0..7679
        int row = p / 120, c = p - row * 120;
        out[(size_t)blockIdx.x * 7680 + p] = s_tab[idxs[row] * 120 + c];
    }
}

// ---------------------------------------------------------------------------
// Exact fallback: np-exact math over flagged rows, 16 rows/block, grid 1024.
// [proven round 9 verbatim]
// ---------------------------------------------------------------------------
__global__ __launch_bounds__(256)
void vq_exact(const float* __restrict__ x,
              const float* __restrict__ w1, const float* __restrict__ b1,
              const float* __restrict__ w2, const float* __restrict__ b2,
              const float* __restrict__ ew3, const float* __restrict__ eb3,
              const float* __restrict__ cb,
              const float* __restrict__ s_tab,
              const float* __restrict__ cbT, const float* __restrict__ cnorm,
              const int* __restrict__ flag_count, const int* __restrict__ flag_list,
              float* __restrict__ out)
{
    __shared__ float act[256 * 18];
    __shared__ float zrm[16 * 68];
    __shared__ float dmr[16 * 68];
    __shared__ float A_lds[16];
    __shared__ int   idxs[16];
    __shared__ int   rl[16];

    const int t = threadIdx.x;
    int count = *flag_count;
    if (count > B_TOTAL) count = B_TOTAL;

    const int tx = t & 31;
    const int ty = t >> 5;
    const int r0 = ty * 2;
    const int c0 = tx * 8;
    const int c0d = tx * 2;

    for (int base = blockIdx.x * 16; base < count; base += 1024 * 16) {
        if (t < 16) {
            int li = base + t;
            rl[t] = flag_list[li < count ? li : count - 1];
        }
        __syncthreads();

        for (int i = 0; i < 8; ++i) {
            int p = t + 256 * i;
            if (p < 1920) {
                int r = p / 120;
                int c = p - r * 120;
                act[c * 18 + r] = x[(size_t)rl[r] * 120 + c];
            }
        }
        __syncthreads();

        // GEMM1: K=120
        {
            float acc[2][8];
#pragma unroll
            for (int i = 0; i < 2; ++i)
#pragma unroll
                for (int c = 0; c < 8; ++c) acc[i][c] = 0.f;
#pragma unroll 2
            for (int k = 0; k < 120; ++k) {
                const float2 av = *(const float2*)&act[k * 18 + r0];
                const float4 wv0 = *(const float4*)&w1[k * 256 + c0];
                const float4 wv1 = *(const float4*)&w1[k * 256 + c0 + 4];
                const float a[2] = {av.x, av.y};
                const float wv[8] = {wv0.x, wv0.y, wv0.z, wv0.w, wv1.x, wv1.y, wv1.z, wv1.w};
#pragma unroll
                for (int i = 0; i < 2; ++i)
#pragma unroll
                    for (int c = 0; c < 8; ++c) acc[i][c] = fmaf(a[i], wv[c], acc[i][c]);
            }
            __syncthreads();
            const float4 bv0 = *(const float4*)&b1[c0];
            const float4 bv1 = *(const float4*)&b1[c0 + 4];
            const float bb[8] = {bv0.x, bv0.y, bv0.z, bv0.w, bv1.x, bv1.y, bv1.z, bv1.w};
#pragma unroll
            for (int c = 0; c < 8; ++c)
#pragma unroll
                for (int i = 0; i < 2; ++i)
                    act[(c0 + c) * 18 + r0 + i] = fmaxf(acc[i][c] + bb[c], 0.f);
        }
        __syncthreads();

        // GEMM2: K=256
        {
            float acc[2][8];
#pragma unroll
            for (int i = 0; i < 2; ++i)
#pragma unroll
                for (int c = 0; c < 8; ++c) acc[i][c] = 0.f;
#pragma unroll 2
            for (int k = 0; k < 256; ++k) {
                const float2 av = *(const float2*)&act[k * 18 + r0];
                const float4 wv0 = *(const float4*)&w2[k * 256 + c0];
                const float4 wv1 = *(const float4*)&w2[k * 256 + c0 + 4];
                const float a[2] = {av.x, av.y};
                const float wv[8] = {wv0.x, wv0.y, wv0.z, wv0.w, wv1.x, wv1.y, wv1.z, wv1.w};
#pragma unroll
                for (int i = 0; i < 2; ++i)
#pragma unroll
                    for (int c = 0; c < 8; ++c) acc[i][c] = fmaf(a[i], wv[c], acc[i][c]);
            }
            __syncthreads();
            const float4 bv0 = *(const float4*)&b2[c0];
            const float4 bv1 = *(const float4*)&b2[c0 + 4];
            const float bb[8] = {bv0.x, bv0.y, bv0.z, bv0.w, bv1.x, bv1.y, bv1.z, bv1.w};
#pragma unroll
            for (int c = 0; c < 8; ++c)
#pragma unroll
                for (int i = 0; i < 2; ++i)
                    act[(c0 + c) * 18 + r0 + i] = fmaxf(acc[i][c] + bb[c], 0.f);
        }
        __syncthreads();

        // GEMM3: K=256, 64 cols
        {
            float acc2[2][2];
#pragma unroll
            for (int i = 0; i < 2; ++i) { acc2[i][0] = 0.f; acc2[i][1] = 0.f; }
#pragma unroll 2
            for (int k = 0; k < 256; ++k) {
                const float2 av = *(const float2*)&act[k * 18 + r0];
                const float2 wv = *(const float2*)&ew3[k * 64 + c0d];
#pragma unroll
                for (int i = 0; i < 2; ++i) {
                    float a = (i == 0) ? av.x : av.y;
                    acc2[i][0] = fmaf(a, wv.x, acc2[i][0]);
                    acc2[i][1] = fmaf(a, wv.y, acc2[i][1]);
                }
            }
            __syncthreads();
            const float2 bv = *(const float2*)&eb3[c0d];
#pragma unroll
            for (int i = 0; i < 2; ++i) {
                float z0 = acc2[i][0] + bv.x;
                float z1 = acc2[i][1] + bv.y;
                act[(c0d + 0) * 18 + r0 + i] = z0;
                act[(c0d + 1) * 18 + r0 + i] = z1;
                zrm[(r0 + i) * 68 + c0d]     = z0;
                zrm[(r0 + i) * 68 + c0d + 1] = z1;
            }
        }
        __syncthreads();

        if (t < 16) A_lds[t] = np_sumsq64(&zrm[t * 68]);
        __syncthreads();

        {
            float acc3[2][2];
#pragma unroll
            for (int i = 0; i < 2; ++i) { acc3[i][0] = 0.f; acc3[i][1] = 0.f; }
#pragma unroll 2
            for (int k = 0; k < 64; ++k) {
                const float2 av = *(const float2*)&act[k * 18 + r0];
                const float2 wv = *(const float2*)&cbT[k * 64 + c0d];
#pragma unroll
                for (int i = 0; i < 2; ++i) {
                    float a = (i == 0) ? av.x : av.y;
                    acc3[i][0] = fmaf(a, wv.x, acc3[i][0]);
                    acc3[i][1] = fmaf(a, wv.y, acc3[i][1]);
                }
            }
            const float cn0 = cnorm[c0d], cn1 = cnorm[c0d + 1];
#pragma unroll
            for (int i = 0; i < 2; ++i) {
                float g0 = 2.0f * acc3[i][0];  asm volatile("" : "+v"(g0));
                float g1 = 2.0f * acc3[i][1];  asm volatile("" : "+v"(g1));
                const float Ar = A_lds[r0 + i];
                dmr[(r0 + i) * 68 + c0d]     = (Ar - g0) + cn0;
                dmr[(r0 + i) * 68 + c0d + 1] = (Ar - g1) + cn1;
            }
        }
        __syncthreads();

        if (t < 16) {
            const float* dr = &dmr[t * 68];
            float best = dr[0];
            int bi = 0;
            for (int c = 1; c < 64; ++c) {
                float v = dr[c];
                if (v < best) { best = v; bi = c; }
            }
            idxs[t] = bi;
            out[AB + rl[t]] = (float)bi;
        }
        __syncthreads();

        {
            const int r = t >> 4, q = t & 15;
            *(float4*)(out + ZB + (size_t)rl[r] * 64 + q * 4) = *(const float4*)&zrm[r * 68 + q * 4];
        }
        {
            const int r = t >> 4, q = t & 15;
            *(float4*)(out + EB + (size_t)rl[r] * 64 + q * 4) = *(const float4*)(cb + idxs[r] * 64 + q * 4);
        }
        for (int i = 0; i < 8; ++i) {
            int p = t + 256 * i;
            if (p < 1920) {
                int r = p / 120;
                int c = p - r * 120;
                out[(size_t)rl[r] * 120 + c] = s_tab[idxs[r] * 120 + c];
            }
        }
        __syncthreads();
    }
}

// ---------------------------------------------------------------------------
extern "C" void kernel_launch(void* const* d_in, const int* in_sizes, int n_in,
                              void* d_out, int out_size, void* d_ws, size_t ws_size,
                              hipStream_t stream)
{
    const float* x   = (const float*)d_in[0];
    const float* w1  = (const float*)d_in[1];
    const float* b1  = (const float*)d_in[2];
    const float* w2  = (const float*)d_in[3];
    const float* b2  = (const float*)d_in[4];
    const float* ew3 = (const float*)d_in[5];
    const float* eb3 = (const float*)d_in[6];
    const float* cb  = (const float*)d_in[7];
    const float* dw3 = (const float*)d_in[8];
    const float* db3 = (const float*)d_in[9];
    const float* dw4 = (const float*)d_in[10];
    const float* db4 = (const float*)d_in[11];
    const float* dw5 = (const float*)d_in[12];
    const float* db5 = (const float*)d_in[13];

    float* out = (float*)d_out;
    char* ws = (char*)d_ws;
    float* s_tab = (float*)(ws + WS_STAB);
    float* cbT   = (float*)(ws + WS_CBT);
    float* cnorm = (float*)(ws + WS_CNORM);
    int*   fcnt  = (int*)(ws + WS_COUNT);
    int*   flist = (int*)(ws + WS_LIST);
    unsigned short* pw1 = (unsigned short*)(ws + WS_PKW1);
    unsigned short* pw2 = (unsigned short*)(ws + WS_PKW2);
    unsigned short* pe3 = (unsigned short*)(ws + WS_PKE3);
    unsigned short* pw4 = (unsigned short*)(ws + WS_PKW4);
    float* cn2 = (float*)(ws + WS_CN2);

    vq_prep<<<64, 256, 0, stream>>>(cb, dw3, db3, dw4, db4, dw5, db5,
                                    s_tab, cbT, cnorm);
    vq_pack<<<256, 512, 0, stream>>>(w1, w2, ew3, cb, eb3,
                                     pw1, pw2, pe3, pw4, cn2, fcnt);
    vq_fast<<<B_TOTAL / 64, 512, 0, stream>>>(x, b1, b2, eb3, cb, s_tab, cn2,
                                              pw1, pw2, pe3, pw4, fcnt, flist, out);
    vq_exact<<<1024, 256, 0, stream>>>(x, w1, b1, w2, b2, ew3, eb3, cb,
                                       s_tab, cbT, cnorm, fcnt, flist, out);
}